// Round 4
// baseline (7486.197 us; speedup 1.0000x reference)
//
#include <hip/hip_runtime.h>
#include <cmath>

constexpr int SEQ = 64;    // sequence length
constexpr int NB  = 128;   // batch
constexpr int H   = 256;   // hidden
constexpr int DIN = 128;   // composed token dim
constexpr int DE  = 256;   // word emb dim
constexpr int NA  = 64;    // actions
constexpr int S1  = 41;    // STACK_SIZE+1
constexpr int S2  = 42;    // slots incl trash slot 41 (unconditional writes)
constexpr int MS  = 100;   // max steps
constexpr int G4  = 1024;  // 4*H

__device__ __forceinline__ float sigf(float x){ return 1.0f/(1.0f+expf(-x)); }

// group barrier: device-scope atomics + fences. All 256 blocks co-resident
// (1 block/CU via launch_bounds + LDS), so spinning is safe.
__device__ __forceinline__ void gbar(unsigned* c, unsigned tgt){
  __syncthreads();
  if (threadIdx.x == 0){
    __threadfence();
    __hip_atomic_fetch_add(c, 1u, __ATOMIC_ACQ_REL, __HIP_MEMORY_SCOPE_AGENT);
    while (__hip_atomic_load(c, __ATOMIC_ACQUIRE, __HIP_MEMORY_SCOPE_AGENT) < tgt)
      __builtin_amdgcn_s_sleep(16);
    __threadfence();
  }
  __syncthreads();
}

// ---------------- transpose: in [R][C] -> out [C][R]
__global__ void transpose_k(const float* __restrict__ in, float* __restrict__ out,
                            int R, int C){
  __shared__ float t[32][33];
  int bx = blockIdx.x*32, by = blockIdx.y*32;
  int x = threadIdx.x, y = threadIdx.y;   // block 32x8
  #pragma unroll
  for (int j = 0; j < 32; j += 8)
    t[y+j][x] = in[(size_t)(by+y+j)*C + bx + x];
  __syncthreads();
  #pragma unroll
  for (int j = 0; j < 32; j += 8)
    out[(size_t)(bx+y+j)*R + by + x] = t[x][y+j];
}

// permuted transpose for [1024][256] weights -> [256][1024] with slice-major rows:
// out[c][ jj*128 + q*32 + r ] = in[ q*256 + jj*32 + r ][ c ]
__global__ void perm_transpose_k(const float* __restrict__ in, float* __restrict__ out){
  __shared__ float t[32][33];
  int bx = blockIdx.x*32;            // c-tile base
  int m  = blockIdx.y;               // source row-chunk (32 rows)
  int q = m >> 3, jj = m & 7;
  int by = q*256 + jj*32;            // source row base
  int nb = jj*128 + q*32;            // dest (permuted) row base
  int x = threadIdx.x, y = threadIdx.y;
  #pragma unroll
  for (int j = 0; j < 32; j += 8)
    t[y+j][x] = in[(size_t)(by+y+j)*256 + bx + x];
  __syncthreads();
  #pragma unroll
  for (int j = 0; j < 32; j += 8)
    out[(size_t)(bx+y+j)*1024 + nb + x] = t[x][y+j];
}

// hist_xz[a][r] = hist_Wih[r,:] . action_emb[a,:] + hist_bih[r] + hist_bhh[r]
__global__ void hist_proj_kernel(const float* __restrict__ Wih,
                                 const float* __restrict__ bih,
                                 const float* __restrict__ bhh,
                                 const float* __restrict__ aemb,
                                 float* __restrict__ out){
  int a = blockIdx.x, t = threadIdx.x;
  __shared__ float e[64];
  if (t < 64) e[t] = aemb[a*64 + t];
  __syncthreads();
  for (int r = t; r < G4; r += blockDim.x){
    const float* w = Wih + r*64;
    float acc = bih[r] + bhh[r];
    #pragma unroll
    for (int k = 0; k < 64; k += 4)
      acc += w[k]*e[k] + w[k+1]*e[k+1] + w[k+2]*e[k+2] + w[k+3]*e[k+3];
    out[a*G4 + r] = acc;
  }
}

// one-time projections of h0. Wt_st_r is the PERMUTED layout, so pz0 comes out
// in permuted row ordering (matching the step kernel's slice reads).
__global__ void h0_proj_kernel(const float* __restrict__ Wt_st_r,  // [256][1024] perm
                               const float* __restrict__ Wt_sum,   // [768][256]
                               const float* __restrict__ h0,
                               float* __restrict__ pz0,            // [1024] perm order
                               double* __restrict__ psum0,         // [256]
                               float* __restrict__ ysumb0){        // [256]
  __shared__ float h0l[H];
  const int t = threadIdx.x;   // 256 threads
  h0l[t] = h0[t];
  __syncthreads();
  float4 acc = make_float4(0.f,0.f,0.f,0.f);
  for (int c = 0; c < H; ++c){
    float4 w = ((const float4*)(Wt_st_r + (size_t)c*G4))[t];
    float x = h0l[c];
    acc.x += w.x*x; acc.y += w.y*x; acc.z += w.z*x; acc.w += w.w*x;
  }
  ((float4*)pz0)[t] = acc;
  double a0 = 0.0, a1 = 0.0;
  for (int c = 0; c < H; ++c){
    double x = (double)h0l[c];
    a0 += (double)Wt_sum[(size_t)c*H + t] * x;          // s-part
    a1 += (double)Wt_sum[(size_t)(H + c)*H + t] * x;    // b-part
  }
  psum0[t] = a0;
  ysumb0[t] = (float)a1;
}

// ---------------- prologue: per-element P0a/P0b/P1 + ysumb + slot-0 init.
// (verbatim round-3, correctness-validated)
__global__ __launch_bounds__(1024, 1)
void prologue_kernel(const int* __restrict__ tokens,
                     const float* __restrict__ word_emb,
                     const float* __restrict__ Wt_cmp,   // [256][128]
                     const float* __restrict__ compose_b,
                     const float* __restrict__ h0,
                     const float* __restrict__ c0,
                     const float* __restrict__ Wt_pbih,  // [128][1024]
                     const float* __restrict__ Wt_pb,    // [256][1024]
                     const float* __restrict__ pb_bih,
                     const float* __restrict__ pb_bhh,
                     const float* __restrict__ Wt_stih,  // [128][1024]
                     const float* __restrict__ st_bih,
                     const float* __restrict__ st_bhh,
                     const float* __restrict__ Wt_sum,   // [768][256]
                     float* __restrict__ pb_zx,   // [B][64][1024]; arena reused for pzs/psums
                     float* __restrict__ st_zx,   // [B][65][1024] (row 64 = bias only)
                     float* __restrict__ bufh,    // [B][64][256]
                     float* __restrict__ scst,    // [B][42][256]
                     float* __restrict__ ysumb_g, // [B][65][256]
                     const float* __restrict__ pz0,
                     const double* __restrict__ psum0,
                     const float* __restrict__ ysumb0)
{
  __shared__ __align__(16) float A[8192];
  __shared__ __align__(16) float Bx[4096];
  __shared__ __align__(16) float ahl[H];
  __shared__ __align__(16) float acl[H];
  __shared__ __align__(16) float h0l[H];

  const int b   = blockIdx.x;
  const int tid = threadIdx.x;

  float* tokl = A;               // [64][128] during P0
  float* embs = Bx;              // [16][256] during P0a

  float*  pzs_b   = pb_zx + (size_t)b*SEQ*G4;
  double* psums_b = (double*)(pzs_b + (size_t)S2*G4);
  float*  pbzx_b  = pb_zx + (size_t)b*SEQ*G4;
  float*  stzx_b  = st_zx + (size_t)b*(SEQ+1)*G4;
  float*  bufh_b  = bufh  + (size_t)b*SEQ*H;
  float*  scst_b  = scst  + (size_t)b*S2*H;
  float*  ysumb_b = ysumb_g + (size_t)b*65*H;

  if (tid < H) h0l[tid] = h0[tid];
  __syncthreads();

  // ---------------- P0a
  {
    const int d = tid & 127, tb = tid >> 7;
    const float cb = compose_b[d];
    for (int pass = 0; pass < 4; ++pass){
      for (int j = tid >> 8; j < 16; j += 4){
        int tt = pass*16 + j;
        int id = tokens[tt*NB + b];
        embs[j*DE + (tid & 255)] = word_emb[(size_t)id*DE + (tid & 255)];
      }
      __syncthreads();
      float a0 = 0.f, a1 = 0.f;
      const float* eb = embs + (tb*2)*DE;
      for (int c = 0; c < DE; ++c){
        float w = Wt_cmp[c*DIN + d];
        a0 += w*eb[c]; a1 += w*eb[DE + c];
      }
      int t0 = pass*16 + tb*2;
      tokl[(t0    )*DIN + d] = fmaxf(a0 + cb, 0.f);
      tokl[(t0 + 1)*DIN + d] = fmaxf(a1 + cb, 0.f);
      __syncthreads();
    }
  }

  // ---------------- P0b
  {
    const int m  = tid >> 9;
    const int lt = tid & 255;
    const int sub = (tid >> 8) & 1;
    const float* Wt  = m ? Wt_stih : Wt_pbih;
    float*       zxb = m ? stzx_b : pbzx_b;
    const float* bA  = m ? st_bih : pb_bih;
    const float* bB  = m ? st_bhh : pb_bhh;
    float4 x1 = ((const float4*)bA)[lt], x2 = ((const float4*)bB)[lt];
    float bx = x1.x + x2.x, by = x1.y + x2.y, bz = x1.z + x2.z, bw = x1.w + x2.w;
    for (int blk = 0; blk < 4; ++blk){
      float ax[8], ay[8], az[8], aw[8];
      #pragma unroll
      for (int t = 0; t < 8; ++t){ ax[t]=0.f; ay[t]=0.f; az[t]=0.f; aw[t]=0.f; }
      const float* tb = tokl + (blk*16 + sub*8)*DIN;
      for (int c = 0; c < DIN; ++c){
        float4 w = ((const float4*)(Wt + (size_t)c*G4))[lt];
        #pragma unroll
        for (int t = 0; t < 8; ++t){
          float x = tb[t*DIN + c];
          ax[t] += w.x*x; ay[t] += w.y*x; az[t] += w.z*x; aw[t] += w.w*x;
        }
      }
      #pragma unroll
      for (int t = 0; t < 8; ++t){
        float4 r = make_float4(ax[t]+bx, ay[t]+by, az[t]+bz, aw[t]+bw);
        ((float4*)(zxb + (size_t)(blk*16 + sub*8 + t)*G4))[lt] = r;
      }
    }
    if (m == 1 && sub == 0)
      ((float4*)(zxb + (size_t)SEQ*G4))[lt] = make_float4(bx, by, bz, bw);
  }
  __syncthreads();

  // ---------------- P1: pre-buffer LSTM over reversed tokens
  if (tid < H){ ahl[tid] = h0l[tid]; acl[tid] = c0[tid]; }
  __syncthreads();
  for (int k = 0; k < SEQ; ++k){
    const int tt = SEQ - 1 - k;
    {
      const int q = tid & 255, cg = tid >> 8;
      float a0=0.f, a1=0.f, a2=0.f, a3=0.f;
      const int cb2 = cg*64;
      for (int c = cb2; c < cb2 + 64; ++c){
        float4 w = ((const float4*)(Wt_pb + (size_t)c*G4))[q];
        float x = ahl[c];
        a0 += w.x*x; a1 += w.y*x; a2 += w.z*x; a3 += w.w*x;
      }
      ((float4*)(A + cg*G4))[q] = make_float4(a0, a1, a2, a3);
    }
    __syncthreads();
    if (tid < H){
      const float* zx = pbzx_b + (size_t)tt*G4;
      float zi_ = A[tid]     + A[G4+tid]     + A[2*G4+tid]     + A[3*G4+tid]     + zx[tid];
      float zf_ = A[H+tid]   + A[G4+H+tid]   + A[2*G4+H+tid]   + A[3*G4+H+tid]   + zx[H+tid];
      float zg_ = A[2*H+tid] + A[G4+2*H+tid] + A[2*G4+2*H+tid] + A[3*G4+2*H+tid] + zx[2*H+tid];
      float zo_ = A[3*H+tid] + A[G4+3*H+tid] + A[2*G4+3*H+tid] + A[3*G4+3*H+tid] + zx[3*H+tid];
      float c2 = sigf(zf_)*acl[tid] + sigf(zi_)*tanhf(zg_);
      float h2 = sigf(zo_)*tanhf(c2);
      acl[tid] = c2; ahl[tid] = h2;
      bufh_b[(size_t)k*H + tid] = h2;
    }
    __syncthreads();
  }
  // pb_zx rows dead now; arena (pzs/psums) writable.

  // ---------------- slot-0 init + scst init
  if (tid < 256) ((float4*)pzs_b)[tid] = ((const float4*)pz0)[tid];   // perm order
  if (tid < 256) psums_b[tid] = psum0[tid];
  if (tid < 64)  ((float4*)ysumb_b)[tid] = ((const float4*)ysumb0)[tid];
  for (int i = tid; i < S2*H; i += 1024) scst_b[i] = (i < H) ? c0[i] : 0.f;

  // ---------------- ysumb[j] = Wsum_b @ bufh[j-1], j=1..64 (f64 acc)
  {
    const int lt = tid & 63, wv = tid >> 6;
    double a00=0,a01=0,a02=0,a03=0, a10=0,a11=0,a12=0,a13=0;
    double a20=0,a21=0,a22=0,a23=0, a30=0,a31=0,a32=0,a33=0;
    for (int c = 0; c < H; ++c){
      float4 w = ((const float4*)(Wt_sum + (size_t)(H + c)*H))[lt];
      double x0 = (double)bufh_b[(size_t)(wv     )*H + c];
      double x1 = (double)bufh_b[(size_t)(wv + 16)*H + c];
      double x2 = (double)bufh_b[(size_t)(wv + 32)*H + c];
      double x3 = (double)bufh_b[(size_t)(wv + 48)*H + c];
      a00+=(double)w.x*x0; a01+=(double)w.y*x0; a02+=(double)w.z*x0; a03+=(double)w.w*x0;
      a10+=(double)w.x*x1; a11+=(double)w.y*x1; a12+=(double)w.z*x1; a13+=(double)w.w*x1;
      a20+=(double)w.x*x2; a21+=(double)w.y*x2; a22+=(double)w.z*x2; a23+=(double)w.w*x2;
      a30+=(double)w.x*x3; a31+=(double)w.y*x3; a32+=(double)w.z*x3; a33+=(double)w.w*x3;
    }
    ((float4*)(ysumb_b + (size_t)(wv+ 1)*H))[lt] = make_float4((float)a00,(float)a01,(float)a02,(float)a03);
    ((float4*)(ysumb_b + (size_t)(wv+17)*H))[lt] = make_float4((float)a10,(float)a11,(float)a12,(float)a13);
    ((float4*)(ysumb_b + (size_t)(wv+33)*H))[lt] = make_float4((float)a20,(float)a21,(float)a22,(float)a23);
    ((float4*)(ysumb_b + (size_t)(wv+49)*H))[lt] = make_float4((float)a30,(float)a31,(float)a32,(float)a33);
  }
}

// ---------------- step kernel: 256 blocks x 1024 thr. Group = 8 blocks (one
// per XCD, j = blockIdx&7 = row-slice id) serving 4 elements. Each block owns
// h-slice [32j,32j+32) => all slot caches owner-local. 3 group barriers/step.
__global__ __launch_bounds__(1024, 1)
void step_kernel(const float* __restrict__ Wst_r,   // [256][1024] perm rows
                 const float* __restrict__ Whi_r,   // [256][1024] perm rows
                 const float* __restrict__ Wt_sum,  // [768][256]
                 const float* __restrict__ Wt_act,  // [256][64]
                 const float* __restrict__ act_b,
                 const float* __restrict__ sum_b,
                 const int* __restrict__ stack_map,
                 const int* __restrict__ buffer_map,
                 const float* __restrict__ histxz,  // [64][1024] original order
                 const float* __restrict__ h0,
                 const float* __restrict__ c0,
                 float* __restrict__ pb_zx,         // arena: pzs[42][1024](perm) + psums[42][256] f64
                 const float* __restrict__ st_zx,   // [B][65][1024] original order
                 float* __restrict__ scst,          // [B][42][256]
                 const float* __restrict__ ysumb_g, // [B][65][256]
                 float* __restrict__ ahg,           // [B][256]
                 float* __restrict__ h2g,           // [B][256]
                 float* __restrict__ summg,         // [B][256]
                 int*   __restrict__ actg,          // [B]
                 unsigned* __restrict__ bars,       // [32 groups][32]
                 float* __restrict__ out)           // [100][128][64]
{
  __shared__ __align__(16) float  ahT[256][4];
  __shared__ __align__(16) float  h2T[256][4];
  __shared__ __align__(16) float  Zp[8][128][4];   // hist-z partials
  __shared__ __align__(16) float  Pp[8][128][4];   // pz partials
  __shared__ __align__(16) double SUp[8][32][4];   // suma partials
  __shared__ __align__(16) double SPp[8][32][4];   // psums partials
  __shared__ __align__(16) double Ld[16][64];      // logits partials
  __shared__ __align__(16) float  achL[4][32];     // hist c slice (owner-local)
  __shared__ int ictl[4][4];   // per elem: spos, bpos, sinc, sp1

  const int tid = threadIdx.x;
  const int j   = blockIdx.x & 7;        // row-slice id (== XCD under rr dispatch)
  const int g   = blockIdx.x >> 3;       // group
  const int ge0 = g*4;

  unsigned* bar1 = bars + g*32 + 0;
  unsigned* bar2 = bars + g*32 + 1;
  unsigned* bar3 = bars + g*32 + 2;

  if (tid < 128) achL[tid>>5][tid&31] = c0[32*j + (tid&31)];
  if (tid < 4){ ictl[tid][0] = 0; ictl[tid][1] = SEQ; ictl[tid][2] = SEQ - 1; ictl[tid][3] = 1; }
  __syncthreads();

  for (int step = 0; step < MS; ++step){
    // ---- phase 0: load full ah / h2 vectors (cross-block, fenced by bar3/bar1)
    {
      const int e = tid >> 8, h = tid & 255;
      ahT[h][e] = (step == 0) ? h0[h] : ahg[(size_t)(ge0+e)*H + h];
      if (step) h2T[h][e] = h2g[(size_t)(ge0+e)*H + h];
    }
    __syncthreads();

    // ---- P1a: action-independent matvec partials over this block's row slice
    {
      const int rl = tid & 127, cg = tid >> 7;
      const float* W = Whi_r + (size_t)(cg*32)*G4 + j*128 + rl;
      float a0=0.f,a1=0.f,a2=0.f,a3=0.f;
      #pragma unroll 8
      for (int c = 0; c < 32; ++c){
        float w = W[(size_t)c*G4];
        float4 x = *(const float4*)&ahT[cg*32 + c][0];
        a0 += w*x.x; a1 += w*x.y; a2 += w*x.z; a3 += w*x.w;
      }
      *(float4*)&Zp[cg][rl][0] = make_float4(a0,a1,a2,a3);
    }
    if (step){
      const int rl = tid & 127, cg = tid >> 7;
      const float* W = Wst_r + (size_t)(cg*32)*G4 + j*128 + rl;
      float a0=0.f,a1=0.f,a2=0.f,a3=0.f;
      #pragma unroll 8
      for (int c = 0; c < 32; ++c){
        float w = W[(size_t)c*G4];
        float4 x = *(const float4*)&h2T[cg*32 + c][0];
        a0 += w*x.x; a1 += w*x.y; a2 += w*x.z; a3 += w*x.w;
      }
      *(float4*)&Pp[cg][rl][0] = make_float4(a0,a1,a2,a3);
    }
    {
      const int r = tid & 31, e = (tid>>5)&3, cg = tid >> 7;
      const float* W = Wt_sum + (size_t)(512 + cg*32)*H + 32*j + r;
      double a = 0.0;
      #pragma unroll 8
      for (int c = 0; c < 32; ++c)
        a += (double)W[(size_t)c*H] * (double)ahT[cg*32 + c][e];
      SUp[cg][r][e] = a;
    }
    if (step){
      const int r = tid & 31, e = (tid>>5)&3, cg = tid >> 7;
      const float* W = Wt_sum + (size_t)(cg*32)*H + 32*j + r;
      double a = 0.0;
      #pragma unroll 8
      for (int c = 0; c < 32; ++c)
        a += (double)W[(size_t)c*H] * (double)h2T[cg*32 + c][e];
      SPp[cg][r][e] = a;
    }
    __syncthreads();

    // ---- P1b-alpha: commit pz/psums of prev h2 into slot sp1 (owner-local)
    if (step){
      if (tid < 512){
        const int rl = tid & 127, e = tid >> 7;
        float v = ((Zp[0][0][0]*0.f)) ; // placeholder avoided below
        v = Pp[0][rl][e] + Pp[1][rl][e] + Pp[2][rl][e] + Pp[3][rl][e]
          + Pp[4][rl][e] + Pp[5][rl][e] + Pp[6][rl][e] + Pp[7][rl][e];
        float* pzs_e = pb_zx + (size_t)(ge0+e)*SEQ*G4;
        pzs_e[(size_t)ictl[e][3]*G4 + j*128 + rl] = v;
      } else if (tid < 640){
        const int t2 = tid - 512, r = t2 & 31, e = t2 >> 5;
        double v = SPp[0][r][e] + SPp[1][r][e] + SPp[2][r][e] + SPp[3][r][e]
                 + SPp[4][r][e] + SPp[5][r][e] + SPp[6][r][e] + SPp[7][r][e];
        double* psums_e = (double*)(pb_zx + (size_t)(ge0+e)*SEQ*G4 + (size_t)S2*G4);
        psums_e[(size_t)ictl[e][3]*H + 32*j + r] = v;
      }
      __syncthreads();
    }

    // ---- P1b-beta: st-LSTM gates + summ finalize (read possibly-fresh slots)
    if (tid < 128){
      const int hp = tid & 31, e = tid >> 5;
      const int ge = ge0 + e;
      const int spos = ictl[e][0], sinc = ictl[e][2];
      const float* pzs_e = pb_zx + (size_t)ge*SEQ*G4;
      const float* pz = pzs_e + (size_t)spos*G4 + j*128;
      const float* zx = st_zx + (size_t)ge*(SEQ+1)*G4 + (size_t)sinc*G4;
      float zi = pz[0*32+hp] + zx[0*H + 32*j + hp];
      float zf = pz[1*32+hp] + zx[1*H + 32*j + hp];
      float zg = pz[2*32+hp] + zx[2*H + 32*j + hp];
      float zo = pz[3*32+hp] + zx[3*H + 32*j + hp];
      float* scst_e = scst + (size_t)ge*S2*H;
      float ct = scst_e[(size_t)spos*H + 32*j + hp];
      float c2 = sigf(zf)*ct + sigf(zi)*tanhf(zg);
      float h2 = sigf(zo)*tanhf(c2);
      scst_e[(size_t)(spos+1)*H + 32*j + hp] = c2;   // trash-slot safe if no push
      h2g[(size_t)ge*H + 32*j + hp] = h2;
    } else if (tid < 256){
      const int t2 = tid - 128, r = t2 & 31, e = t2 >> 5;
      const int ge = ge0 + e;
      const int spos = ictl[e][0], bp = ictl[e][1];
      const double* psums_e = (const double*)(pb_zx + (size_t)ge*SEQ*G4 + (size_t)S2*G4);
      double s = SUp[0][r][e] + SUp[1][r][e] + SUp[2][r][e] + SUp[3][r][e]
               + SUp[4][r][e] + SUp[5][r][e] + SUp[6][r][e] + SUp[7][r][e]
               + psums_e[(size_t)spos*H + 32*j + r]
               + (double)ysumb_g[((size_t)ge*65 + bp)*H + 32*j + r]
               + (double)sum_b[32*j + r];
      summg[(size_t)ge*H + 32*j + r] = fmaxf((float)s, 0.f);
    }
    gbar(bar1, 8u*(step+1));

    // ---- P2: logits + softmax + argmax + action (blocks 0-3 of each group)
    if (j < 4){
      const int ge = ge0 + j;
      const int o = tid & 63, cg = tid >> 6;
      double acc = 0.0;
      #pragma unroll 4
      for (int c = 0; c < 16; ++c)
        acc += (double)Wt_act[(cg*16 + c)*NA + o] * (double)summg[(size_t)ge*H + cg*16 + c];
      Ld[cg][o] = acc;
      __syncthreads();
      if (tid < 64){
        double v2 = (double)act_b[tid];
        #pragma unroll
        for (int k = 0; k < 16; ++k) v2 += Ld[k][tid];
        float v = (float)v2;
        float mx = v;
        #pragma unroll
        for (int o2 = 32; o2 > 0; o2 >>= 1) mx = fmaxf(mx, __shfl_xor(mx, o2));
        float ex = expf(v - mx), sm = ex;
        #pragma unroll
        for (int o2 = 32; o2 > 0; o2 >>= 1) sm += __shfl_xor(sm, o2);
        out[((size_t)step*NB + ge)*NA + tid] = v - mx - logf(sm);
        float bv = v; int bi = tid;    // argmax, first index wins on ties
        #pragma unroll
        for (int o2 = 32; o2 > 0; o2 >>= 1){
          float ov = __shfl_xor(bv, o2); int oi = __shfl_xor(bi, o2);
          if (ov > bv || (ov == bv && oi < bi)){ bv = ov; bi = oi; }
        }
        if (tid == 0) actg[ge] = bi;
      }
    }
    gbar(bar2, 8u*(step+1));

    // ---- P2c: hist gates (need action) + replicated control update
    if (tid < 128){
      const int hp = tid & 31, e = tid >> 5;
      const int ge = ge0 + e;
      const int a = actg[ge];
      float z0=0.f,z1=0.f,z2=0.f,z3=0.f;
      #pragma unroll
      for (int cg = 0; cg < 8; ++cg){
        z0 += Zp[cg][0*32+hp][e];
        z1 += Zp[cg][1*32+hp][e];
        z2 += Zp[cg][2*32+hp][e];
        z3 += Zp[cg][3*32+hp][e];
      }
      const float* hb = histxz + (size_t)a*G4;
      z0 += hb[0*H + 32*j + hp];
      z1 += hb[1*H + 32*j + hp];
      z2 += hb[2*H + 32*j + hp];
      z3 += hb[3*H + 32*j + hp];
      float hc = achL[e][hp];
      float c2 = sigf(z1)*hc + sigf(z0)*tanhf(z2);
      float h2v = sigf(z3)*tanhf(c2);
      achL[e][hp] = c2;
      ahg[(size_t)ge*H + 32*j + hp] = h2v;
    } else if (tid >= 128 && tid < 132){
      const int e = tid - 128;
      const int ge = ge0 + e;
      const int a = actg[ge];
      int sp = ictl[e][0], bp = ictl[e][1];
      int sop = stack_map[a], bop = buffer_map[a];
      if (sp == 0 && sop == -1) sop = 0;
      if (sp >= S1 - 1 && sop == 1) sop = 0;
      if (bp == 0 && bop == -1) bop = 0;
      int sposn = sp + sop;
      int bposn = bp + bop;
      int ne    = (bposn > 0) ? 1 : 0;
      int gidx  = bposn - 1; if (gidx < 0) gidx = 0; if (gidx > SEQ - 1) gidx = SEQ - 1;
      ictl[e][3] = sp + 1;         // slot for this step's h2 projection (next step)
      ictl[e][0] = sposn; ictl[e][1] = bposn; ictl[e][2] = ne ? gidx : SEQ;
    }
    gbar(bar3, 8u*(step+1));
  }
}

extern "C" void kernel_launch(void* const* d_in, const int* in_sizes, int n_in,
                              void* d_out, int out_size, void* d_ws, size_t ws_size,
                              hipStream_t stream){
  (void)in_sizes; (void)n_in; (void)out_size; (void)ws_size;
  const int*   tokens    = (const int*)  d_in[0];
  const float* word_emb  = (const float*)d_in[1];
  const float* compose_W = (const float*)d_in[2];
  const float* compose_b = (const float*)d_in[3];
  const float* h0        = (const float*)d_in[4];
  const float* c0        = (const float*)d_in[5];
  const float* pb_Wih    = (const float*)d_in[6];
  const float* pb_Whh    = (const float*)d_in[7];
  const float* pb_bih    = (const float*)d_in[8];
  const float* pb_bhh    = (const float*)d_in[9];
  const float* st_Wih    = (const float*)d_in[10];
  const float* st_Whh    = (const float*)d_in[11];
  const float* st_bih    = (const float*)d_in[12];
  const float* st_bhh    = (const float*)d_in[13];
  const float* hist_Wih  = (const float*)d_in[14];
  const float* hist_Whh  = (const float*)d_in[15];
  const float* hist_bih  = (const float*)d_in[16];
  const float* hist_bhh  = (const float*)d_in[17];
  const float* sum_W     = (const float*)d_in[18];
  const float* sum_b     = (const float*)d_in[19];
  const float* act_W     = (const float*)d_in[20];
  const float* act_b     = (const float*)d_in[21];
  const float* action_emb= (const float*)d_in[22];
  const int*   stack_map = (const int*)  d_in[23];
  const int*   buffer_map= (const int*)  d_in[24];

  float* ws     = (float*)d_ws;
  float* pb_zx  = ws;                                  // 128*64*1024 (arena: pzs[42]+psums[42] per elem)
  float* st_zx  = pb_zx + (size_t)NB*SEQ*G4;           // 128*65*1024
  float* bufh   = st_zx + (size_t)NB*(SEQ+1)*G4;       // 128*64*256
  float* scst   = bufh  + (size_t)NB*SEQ*H;            // 128*42*256
  float* histxz = scst  + (size_t)NB*S2*H;             // 64*1024
  float* Wt_pb  = histxz + (size_t)NA*G4;              // [256][1024]
  float* Wst_r  = Wt_pb  + (size_t)H*G4;               // [256][1024] permuted
  float* Whi_r  = Wst_r  + (size_t)H*G4;               // [256][1024] permuted
  float* Wt_sum = Whi_r  + (size_t)H*G4;               // [768][256]
  float* Wt_act = Wt_sum + (size_t)768*H;              // [256][64]
  float* Wt_pbih= Wt_act + (size_t)H*NA;               // [128][1024]
  float* Wt_stih= Wt_pbih+ (size_t)DIN*G4;             // [128][1024]
  float* Wt_cmp = Wt_stih+ (size_t)DIN*G4;             // [256][128]
  float* ysumb  = Wt_cmp + (size_t)DE*DIN;             // [128][65][256]
  float* pz0    = ysumb  + (size_t)NB*65*H;            // [1024]
  double* psum0 = (double*)(pz0 + G4);                 // [256] f64
  float* ysumb0 = (float*)(psum0 + H);                 // [256]
  float* ahg    = ysumb0 + H;                          // [128][256]
  float* h2g    = ahg    + (size_t)NB*H;               // [128][256]
  float* summg  = h2g    + (size_t)NB*H;               // [128][256]
  int*   actg   = (int*)(summg + (size_t)NB*H);        // [128]
  unsigned* bars= (unsigned*)(actg + NB);              // [32][32]

  hipMemsetAsync(bars, 0, 32*32*sizeof(unsigned), stream);

  dim3 blk(32, 8);
  transpose_k<<<dim3(256/32, 1024/32), blk, 0, stream>>>(pb_Whh,   Wt_pb,  1024, 256);
  perm_transpose_k<<<dim3(256/32, 32), blk, 0, stream>>>(st_Whh,   Wst_r);
  perm_transpose_k<<<dim3(256/32, 32), blk, 0, stream>>>(hist_Whh, Whi_r);
  transpose_k<<<dim3(768/32,  256/32), blk, 0, stream>>>(sum_W,    Wt_sum,  256, 768);
  transpose_k<<<dim3(256/32,   64/32), blk, 0, stream>>>(act_W,    Wt_act,   64, 256);
  transpose_k<<<dim3(128/32, 1024/32), blk, 0, stream>>>(pb_Wih,   Wt_pbih,1024, 128);
  transpose_k<<<dim3(128/32, 1024/32), blk, 0, stream>>>(st_Wih,   Wt_stih,1024, 128);
  transpose_k<<<dim3(256/32,  128/32), blk, 0, stream>>>(compose_W,Wt_cmp,  128, 256);
  hist_proj_kernel<<<dim3(NA), dim3(256), 0, stream>>>(hist_Wih, hist_bih, hist_bhh,
                                                       action_emb, histxz);
  h0_proj_kernel<<<dim3(1), dim3(256), 0, stream>>>(Wst_r, Wt_sum, h0, pz0, psum0, ysumb0);

  prologue_kernel<<<dim3(NB), dim3(1024), 0, stream>>>(tokens, word_emb, Wt_cmp, compose_b,
      h0, c0, Wt_pbih, Wt_pb, pb_bih, pb_bhh, Wt_stih, st_bih, st_bhh, Wt_sum,
      pb_zx, st_zx, bufh, scst, ysumb, pz0, psum0, ysumb0);

  step_kernel<<<dim3(256), dim3(1024), 0, stream>>>(Wst_r, Whi_r, Wt_sum, Wt_act,
      act_b, sum_b, stack_map, buffer_map, histxz, h0, c0,
      pb_zx, st_zx, scst, ysumb, ahg, h2g, summg, actg, bars, (float*)d_out);
}

// Round 5
// 5790.744 us; speedup vs baseline: 1.2928x; 1.2928x over previous
//
#include <hip/hip_runtime.h>
#include <cmath>

constexpr int SEQ = 64;    // sequence length
constexpr int NB  = 128;   // batch
constexpr int H   = 256;   // hidden
constexpr int DIN = 128;   // composed token dim
constexpr int DE  = 256;   // word emb dim
constexpr int NA  = 64;    // actions
constexpr int S1  = 41;    // STACK_SIZE+1
constexpr int S2  = 42;    // slots incl trash slot 41 (unconditional writes)
constexpr int MS  = 100;   // max steps
constexpr int G4  = 1024;  // 4*H

__device__ __forceinline__ float sigf(float x){ return 1.0f/(1.0f+expf(-x)); }

// L2-bypassing (fabric-coherent) relaxed atomics for cross-block data.
__device__ __forceinline__ float aload(const float* p){
  return __hip_atomic_load((const float*)p, __ATOMIC_RELAXED, __HIP_MEMORY_SCOPE_AGENT);
}
__device__ __forceinline__ void astore(float* p, float v){
  __hip_atomic_store(p, v, __ATOMIC_RELAXED, __HIP_MEMORY_SCOPE_AGENT);
}

// Cheap group barrier: NO acquire/release cache maintenance. Correctness:
// __syncthreads drains all waves' vmcnt (stores device-visible: all cross-block
// data uses sc0/sc1-bypass atomics, so no stale cached copies exist anywhere);
// then a relaxed fetch_add + relaxed poll. All 256 blocks co-resident (1/CU).
__device__ __forceinline__ void gbarl(unsigned* c, unsigned tgt){
  __syncthreads();
  if (threadIdx.x == 0){
    asm volatile("" ::: "memory");
    __hip_atomic_fetch_add(c, 1u, __ATOMIC_RELAXED, __HIP_MEMORY_SCOPE_AGENT);
    while (__hip_atomic_load(c, __ATOMIC_RELAXED, __HIP_MEMORY_SCOPE_AGENT) < tgt)
      __builtin_amdgcn_s_sleep(1);
    asm volatile("" ::: "memory");
  }
  __syncthreads();
}

// ---------------- transpose: in [R][C] -> out [C][R]
__global__ void transpose_k(const float* __restrict__ in, float* __restrict__ out,
                            int R, int C){
  __shared__ float t[32][33];
  int bx = blockIdx.x*32, by = blockIdx.y*32;
  int x = threadIdx.x, y = threadIdx.y;   // block 32x8
  #pragma unroll
  for (int j = 0; j < 32; j += 8)
    t[y+j][x] = in[(size_t)(by+y+j)*C + bx + x];
  __syncthreads();
  #pragma unroll
  for (int j = 0; j < 32; j += 8)
    out[(size_t)(bx+y+j)*R + by + x] = t[x][y+j];
}

// permuted transpose for [1024][256] weights -> [256][1024] with slice-major rows:
// out[c][ jj*128 + q*32 + r ] = in[ q*256 + jj*32 + r ][ c ]
__global__ void perm_transpose_k(const float* __restrict__ in, float* __restrict__ out){
  __shared__ float t[32][33];
  int bx = blockIdx.x*32;            // c-tile base
  int m  = blockIdx.y;               // source row-chunk (32 rows)
  int q = m >> 3, jj = m & 7;
  int by = q*256 + jj*32;            // source row base
  int nb = jj*128 + q*32;            // dest (permuted) row base
  int x = threadIdx.x, y = threadIdx.y;
  #pragma unroll
  for (int j = 0; j < 32; j += 8)
    t[y+j][x] = in[(size_t)(by+y+j)*256 + bx + x];
  __syncthreads();
  #pragma unroll
  for (int j = 0; j < 32; j += 8)
    out[(size_t)(bx+y+j)*1024 + nb + x] = t[x][y+j];
}

// hist_xz[a][r] = hist_Wih[r,:] . action_emb[a,:] + hist_bih[r] + hist_bhh[r]
__global__ void hist_proj_kernel(const float* __restrict__ Wih,
                                 const float* __restrict__ bih,
                                 const float* __restrict__ bhh,
                                 const float* __restrict__ aemb,
                                 float* __restrict__ out){
  int a = blockIdx.x, t = threadIdx.x;
  __shared__ float e[64];
  if (t < 64) e[t] = aemb[a*64 + t];
  __syncthreads();
  for (int r = t; r < G4; r += blockDim.x){
    const float* w = Wih + r*64;
    float acc = bih[r] + bhh[r];
    #pragma unroll
    for (int k = 0; k < 64; k += 4)
      acc += w[k]*e[k] + w[k+1]*e[k+1] + w[k+2]*e[k+2] + w[k+3]*e[k+3];
    out[a*G4 + r] = acc;
  }
}

// one-time projections of h0. Wt_st_r is the PERMUTED layout, so pz0 comes out
// in permuted row ordering (matching the step kernel's slice reads).
__global__ void h0_proj_kernel(const float* __restrict__ Wt_st_r,  // [256][1024] perm
                               const float* __restrict__ Wt_sum,   // [768][256]
                               const float* __restrict__ h0,
                               float* __restrict__ pz0,            // [1024] perm order
                               double* __restrict__ psum0,         // [256]
                               float* __restrict__ ysumb0){        // [256]
  __shared__ float h0l[H];
  const int t = threadIdx.x;   // 256 threads
  h0l[t] = h0[t];
  __syncthreads();
  float4 acc = make_float4(0.f,0.f,0.f,0.f);
  for (int c = 0; c < H; ++c){
    float4 w = ((const float4*)(Wt_st_r + (size_t)c*G4))[t];
    float x = h0l[c];
    acc.x += w.x*x; acc.y += w.y*x; acc.z += w.z*x; acc.w += w.w*x;
  }
  ((float4*)pz0)[t] = acc;
  double a0 = 0.0, a1 = 0.0;
  for (int c = 0; c < H; ++c){
    double x = (double)h0l[c];
    a0 += (double)Wt_sum[(size_t)c*H + t] * x;          // s-part
    a1 += (double)Wt_sum[(size_t)(H + c)*H + t] * x;    // b-part
  }
  psum0[t] = a0;
  ysumb0[t] = (float)a1;
}

// ---------------- prologue: per-element P0a/P0b/P1 + ysumb + slot-0 init.
// (verbatim round-3/4, correctness-validated)
__global__ __launch_bounds__(1024, 1)
void prologue_kernel(const int* __restrict__ tokens,
                     const float* __restrict__ word_emb,
                     const float* __restrict__ Wt_cmp,   // [256][128]
                     const float* __restrict__ compose_b,
                     const float* __restrict__ h0,
                     const float* __restrict__ c0,
                     const float* __restrict__ Wt_pbih,  // [128][1024]
                     const float* __restrict__ Wt_pb,    // [256][1024]
                     const float* __restrict__ pb_bih,
                     const float* __restrict__ pb_bhh,
                     const float* __restrict__ Wt_stih,  // [128][1024]
                     const float* __restrict__ st_bih,
                     const float* __restrict__ st_bhh,
                     const float* __restrict__ Wt_sum,   // [768][256]
                     float* __restrict__ pb_zx,   // [B][64][1024]; arena reused for pzs/psums
                     float* __restrict__ st_zx,   // [B][65][1024] (row 64 = bias only)
                     float* __restrict__ bufh,    // [B][64][256]
                     float* __restrict__ scst,    // [B][42][256]
                     float* __restrict__ ysumb_g, // [B][65][256]
                     const float* __restrict__ pz0,
                     const double* __restrict__ psum0,
                     const float* __restrict__ ysumb0)
{
  __shared__ __align__(16) float A[8192];
  __shared__ __align__(16) float Bx[4096];
  __shared__ __align__(16) float ahl[H];
  __shared__ __align__(16) float acl[H];
  __shared__ __align__(16) float h0l[H];

  const int b   = blockIdx.x;
  const int tid = threadIdx.x;

  float* tokl = A;               // [64][128] during P0
  float* embs = Bx;              // [16][256] during P0a

  float*  pzs_b   = pb_zx + (size_t)b*SEQ*G4;
  double* psums_b = (double*)(pzs_b + (size_t)S2*G4);
  float*  pbzx_b  = pb_zx + (size_t)b*SEQ*G4;
  float*  stzx_b  = st_zx + (size_t)b*(SEQ+1)*G4;
  float*  bufh_b  = bufh  + (size_t)b*SEQ*H;
  float*  scst_b  = scst  + (size_t)b*S2*H;
  float*  ysumb_b = ysumb_g + (size_t)b*65*H;

  if (tid < H) h0l[tid] = h0[tid];
  __syncthreads();

  // ---------------- P0a
  {
    const int d = tid & 127, tb = tid >> 7;
    const float cb = compose_b[d];
    for (int pass = 0; pass < 4; ++pass){
      for (int j = tid >> 8; j < 16; j += 4){
        int tt = pass*16 + j;
        int id = tokens[tt*NB + b];
        embs[j*DE + (tid & 255)] = word_emb[(size_t)id*DE + (tid & 255)];
      }
      __syncthreads();
      float a0 = 0.f, a1 = 0.f;
      const float* eb = embs + (tb*2)*DE;
      for (int c = 0; c < DE; ++c){
        float w = Wt_cmp[c*DIN + d];
        a0 += w*eb[c]; a1 += w*eb[DE + c];
      }
      int t0 = pass*16 + tb*2;
      tokl[(t0    )*DIN + d] = fmaxf(a0 + cb, 0.f);
      tokl[(t0 + 1)*DIN + d] = fmaxf(a1 + cb, 0.f);
      __syncthreads();
    }
  }

  // ---------------- P0b
  {
    const int m  = tid >> 9;
    const int lt = tid & 255;
    const int sub = (tid >> 8) & 1;
    const float* Wt  = m ? Wt_stih : Wt_pbih;
    float*       zxb = m ? stzx_b : pbzx_b;
    const float* bA  = m ? st_bih : pb_bih;
    const float* bB  = m ? st_bhh : pb_bhh;
    float4 x1 = ((const float4*)bA)[lt], x2 = ((const float4*)bB)[lt];
    float bx = x1.x + x2.x, by = x1.y + x2.y, bz = x1.z + x2.z, bw = x1.w + x2.w;
    for (int blk = 0; blk < 4; ++blk){
      float ax[8], ay[8], az[8], aw[8];
      #pragma unroll
      for (int t = 0; t < 8; ++t){ ax[t]=0.f; ay[t]=0.f; az[t]=0.f; aw[t]=0.f; }
      const float* tb = tokl + (blk*16 + sub*8)*DIN;
      for (int c = 0; c < DIN; ++c){
        float4 w = ((const float4*)(Wt + (size_t)c*G4))[lt];
        #pragma unroll
        for (int t = 0; t < 8; ++t){
          float x = tb[t*DIN + c];
          ax[t] += w.x*x; ay[t] += w.y*x; az[t] += w.z*x; aw[t] += w.w*x;
        }
      }
      #pragma unroll
      for (int t = 0; t < 8; ++t){
        float4 r = make_float4(ax[t]+bx, ay[t]+by, az[t]+bz, aw[t]+bw);
        ((float4*)(zxb + (size_t)(blk*16 + sub*8 + t)*G4))[lt] = r;
      }
    }
    if (m == 1 && sub == 0)
      ((float4*)(zxb + (size_t)SEQ*G4))[lt] = make_float4(bx, by, bz, bw);
  }
  __syncthreads();

  // ---------------- P1: pre-buffer LSTM over reversed tokens
  if (tid < H){ ahl[tid] = h0l[tid]; acl[tid] = c0[tid]; }
  __syncthreads();
  for (int k = 0; k < SEQ; ++k){
    const int tt = SEQ - 1 - k;
    {
      const int q = tid & 255, cg = tid >> 8;
      float a0=0.f, a1=0.f, a2=0.f, a3=0.f;
      const int cb2 = cg*64;
      for (int c = cb2; c < cb2 + 64; ++c){
        float4 w = ((const float4*)(Wt_pb + (size_t)c*G4))[q];
        float x = ahl[c];
        a0 += w.x*x; a1 += w.y*x; a2 += w.z*x; a3 += w.w*x;
      }
      ((float4*)(A + cg*G4))[q] = make_float4(a0, a1, a2, a3);
    }
    __syncthreads();
    if (tid < H){
      const float* zx = pbzx_b + (size_t)tt*G4;
      float zi_ = A[tid]     + A[G4+tid]     + A[2*G4+tid]     + A[3*G4+tid]     + zx[tid];
      float zf_ = A[H+tid]   + A[G4+H+tid]   + A[2*G4+H+tid]   + A[3*G4+H+tid]   + zx[H+tid];
      float zg_ = A[2*H+tid] + A[G4+2*H+tid] + A[2*G4+2*H+tid] + A[3*G4+2*H+tid] + zx[2*H+tid];
      float zo_ = A[3*H+tid] + A[G4+3*H+tid] + A[2*G4+3*H+tid] + A[3*G4+3*H+tid] + zx[3*H+tid];
      float c2 = sigf(zf_)*acl[tid] + sigf(zi_)*tanhf(zg_);
      float h2 = sigf(zo_)*tanhf(c2);
      acl[tid] = c2; ahl[tid] = h2;
      bufh_b[(size_t)k*H + tid] = h2;
    }
    __syncthreads();
  }
  // pb_zx rows dead now; arena (pzs/psums) writable.

  // ---------------- slot-0 init + scst init
  if (tid < 256) ((float4*)pzs_b)[tid] = ((const float4*)pz0)[tid];   // perm order
  if (tid < 256) psums_b[tid] = psum0[tid];
  if (tid < 64)  ((float4*)ysumb_b)[tid] = ((const float4*)ysumb0)[tid];
  for (int i = tid; i < S2*H; i += 1024) scst_b[i] = (i < H) ? c0[i] : 0.f;

  // ---------------- ysumb[j] = Wsum_b @ bufh[j-1], j=1..64 (f64 acc)
  {
    const int lt = tid & 63, wv = tid >> 6;
    double a00=0,a01=0,a02=0,a03=0, a10=0,a11=0,a12=0,a13=0;
    double a20=0,a21=0,a22=0,a23=0, a30=0,a31=0,a32=0,a33=0;
    for (int c = 0; c < H; ++c){
      float4 w = ((const float4*)(Wt_sum + (size_t)(H + c)*H))[lt];
      double x0 = (double)bufh_b[(size_t)(wv     )*H + c];
      double x1 = (double)bufh_b[(size_t)(wv + 16)*H + c];
      double x2 = (double)bufh_b[(size_t)(wv + 32)*H + c];
      double x3 = (double)bufh_b[(size_t)(wv + 48)*H + c];
      a00+=(double)w.x*x0; a01+=(double)w.y*x0; a02+=(double)w.z*x0; a03+=(double)w.w*x0;
      a10+=(double)w.x*x1; a11+=(double)w.y*x1; a12+=(double)w.z*x1; a13+=(double)w.w*x1;
      a20+=(double)w.x*x2; a21+=(double)w.y*x2; a22+=(double)w.z*x2; a23+=(double)w.w*x2;
      a30+=(double)w.x*x3; a31+=(double)w.y*x3; a32+=(double)w.z*x3; a33+=(double)w.w*x3;
    }
    ((float4*)(ysumb_b + (size_t)(wv+ 1)*H))[lt] = make_float4((float)a00,(float)a01,(float)a02,(float)a03);
    ((float4*)(ysumb_b + (size_t)(wv+17)*H))[lt] = make_float4((float)a10,(float)a11,(float)a12,(float)a13);
    ((float4*)(ysumb_b + (size_t)(wv+33)*H))[lt] = make_float4((float)a20,(float)a21,(float)a22,(float)a23);
    ((float4*)(ysumb_b + (size_t)(wv+49)*H))[lt] = make_float4((float)a30,(float)a31,(float)a32,(float)a33);
  }
}

// ---------------- step kernel: 256 blocks x 1024 thr. Group = 8 blocks
// (j = blockIdx&7 = row-slice id) serving 4 elements. Slot caches owner-local.
// 2 relaxed group barriers/step; cross-block data via fabric-coherent relaxed
// atomics (no cache invalidation -> weights stay L2-hot). Logits/argmax/control
// computed REPLICATED (bit-identical) in all 8 blocks: no action broadcast.
__global__ __launch_bounds__(1024, 1)
void step_kernel(const float* __restrict__ Wst_r,   // [256][1024] perm rows
                 const float* __restrict__ Whi_r,   // [256][1024] perm rows
                 const float* __restrict__ Wt_sum,  // [768][256]
                 const float* __restrict__ Wt_act,  // [256][64]
                 const float* __restrict__ act_b,
                 const float* __restrict__ sum_b,
                 const int* __restrict__ stack_map,
                 const int* __restrict__ buffer_map,
                 const float* __restrict__ histxz,  // [64][1024] original order
                 const float* __restrict__ h0,
                 const float* __restrict__ c0,
                 float* __restrict__ pb_zx,         // arena: pzs[42][1024](perm) + psums[42][256] f64
                 const float* __restrict__ st_zx,   // [B][65][1024] original order
                 float* __restrict__ scst,          // [B][42][256]
                 const float* __restrict__ ysumb_g, // [B][65][256]
                 float* __restrict__ ahg,           // [B][256]
                 float* __restrict__ h2g,           // [2][B][256] (step-parity dbuf)
                 float* __restrict__ summg,         // [B][256]
                 unsigned* __restrict__ bars,       // [32 groups]
                 float* __restrict__ out)           // [100][128][64]
{
  __shared__ __align__(16) float  ahT[256][4];
  __shared__ __align__(16) float  h2T[256][4];
  __shared__ __align__(16) float  smT[256][4];
  __shared__ __align__(16) float  Zp[8][4][128];   // hist-z partials [cg][e][row]
  __shared__ __align__(16) float  Pp[8][4][128];   // st-z partials
  __shared__ __align__(16) double SUp[8][4][32];   // suma partials [cg][e][r]
  __shared__ __align__(16) double SPp[8][4][32];   // psums partials
  __shared__ __align__(16) double Ld[4][4][64];    // logits partials [cg][e][o]
  __shared__ __align__(16) float  achL[4][32];     // hist c slice (owner-local)
  __shared__ int ictl[4][4];   // per elem: spos, bpos, sinc, sp1 (commit slot)
  __shared__ int acts[4];

  const int tid = threadIdx.x;
  const int j   = blockIdx.x & 7;        // row-slice id
  const int g   = blockIdx.x >> 3;       // group
  const int ge0 = g*4;
  unsigned* ctr = bars + g;

  if (tid < 128) achL[tid>>5][tid&31] = c0[32*j + (tid&31)];
  if (tid < 4){ ictl[tid][0] = 0; ictl[tid][1] = SEQ; ictl[tid][2] = SEQ - 1; ictl[tid][3] = 1; }
  __syncthreads();

  for (int step = 0; step < MS; ++step){
    // ---- gather ah / prev candidate h2 (fabric reads; parity dbuf for h2)
    {
      const int e = tid >> 8, h = tid & 255;
      ahT[h][e] = (step == 0) ? h0[h] : aload(ahg + (size_t)(ge0+e)*H + h);
      if (step){
        const float* h2src = h2g + (size_t)((step+1)&1)*NB*H;
        h2T[h][e] = aload(h2src + (size_t)(ge0+e)*H + h);
      }
    }
    __syncthreads();

    // ---- A1: hist-z partials over this block's row slice
    {
      const int rl = tid & 127, cg = tid >> 7;
      const float* W = Whi_r + (size_t)(cg*32)*G4 + j*128 + rl;
      float a0=0.f,a1=0.f,a2=0.f,a3=0.f;
      #pragma unroll 8
      for (int c = 0; c < 32; ++c){
        float w = W[(size_t)c*G4];
        float4 x = *(const float4*)&ahT[cg*32 + c][0];
        a0 += w*x.x; a1 += w*x.y; a2 += w*x.z; a3 += w*x.w;
      }
      Zp[cg][0][rl]=a0; Zp[cg][1][rl]=a1; Zp[cg][2][rl]=a2; Zp[cg][3][rl]=a3;
    }
    if (step){
      const int rl = tid & 127, cg = tid >> 7;
      const float* W = Wst_r + (size_t)(cg*32)*G4 + j*128 + rl;
      float a0=0.f,a1=0.f,a2=0.f,a3=0.f;
      #pragma unroll 8
      for (int c = 0; c < 32; ++c){
        float w = W[(size_t)c*G4];
        float4 x = *(const float4*)&h2T[cg*32 + c][0];
        a0 += w*x.x; a1 += w*x.y; a2 += w*x.z; a3 += w*x.w;
      }
      Pp[cg][0][rl]=a0; Pp[cg][1][rl]=a1; Pp[cg][2][rl]=a2; Pp[cg][3][rl]=a3;
    }
    // ---- A2: suma f64 partials
    {
      const int r = tid & 31, e = (tid>>5)&3, cg = tid >> 7;
      const float* W = Wt_sum + (size_t)(512 + cg*32)*H + 32*j + r;
      double a = 0.0;
      #pragma unroll 8
      for (int c = 0; c < 32; ++c)
        a += (double)W[(size_t)c*H] * (double)ahT[cg*32 + c][e];
      SUp[cg][e][r] = a;
    }
    if (step){
      const int r = tid & 31, e = (tid>>5)&3, cg = tid >> 7;
      const float* W = Wt_sum + (size_t)(cg*32)*H + 32*j + r;
      double a = 0.0;
      #pragma unroll 8
      for (int c = 0; c < 32; ++c)
        a += (double)W[(size_t)c*H] * (double)h2T[cg*32 + c][e];
      SPp[cg][e][r] = a;
    }
    __syncthreads();

    // ---- alpha: commit prev h2's projections into slot caches (owner-local)
    if (step){
      if (tid < 512){
        const int rl = tid & 127, e = tid >> 7;
        float v = Pp[0][e][rl] + Pp[1][e][rl] + Pp[2][e][rl] + Pp[3][e][rl]
                + Pp[4][e][rl] + Pp[5][e][rl] + Pp[6][e][rl] + Pp[7][e][rl];
        float* pzs_e = pb_zx + (size_t)(ge0+e)*SEQ*G4;
        pzs_e[(size_t)ictl[e][3]*G4 + j*128 + rl] = v;
      } else if (tid < 640){
        const int t2 = tid - 512, r = t2 & 31, e = t2 >> 5;
        double v = SPp[0][e][r] + SPp[1][e][r] + SPp[2][e][r] + SPp[3][e][r]
                 + SPp[4][e][r] + SPp[5][e][r] + SPp[6][e][r] + SPp[7][e][r];
        double* ps = (double*)(pb_zx + (size_t)(ge0+e)*SEQ*G4 + (size_t)S2*G4);
        ps[(size_t)ictl[e][3]*H + 32*j + r] = v;
      }
      __syncthreads();
    }

    // ---- beta: st-LSTM gates + summ finalize (owner-local slot reads)
    if (tid < 128){
      const int hp = tid & 31, e = tid >> 5;
      const int ge = ge0 + e;
      const int spos = ictl[e][0], sinc = ictl[e][2];
      const float* pz = pb_zx + (size_t)ge*SEQ*G4 + (size_t)spos*G4 + j*128;
      const float* zx = st_zx + (size_t)ge*(SEQ+1)*G4 + (size_t)sinc*G4;
      float zi = pz[0*32+hp] + zx[0*H + 32*j + hp];
      float zf = pz[1*32+hp] + zx[1*H + 32*j + hp];
      float zg = pz[2*32+hp] + zx[2*H + 32*j + hp];
      float zo = pz[3*32+hp] + zx[3*H + 32*j + hp];
      float* scst_e = scst + (size_t)ge*S2*H;
      float ct = scst_e[(size_t)spos*H + 32*j + hp];
      float c2 = sigf(zf)*ct + sigf(zi)*tanhf(zg);
      float h2 = sigf(zo)*tanhf(c2);
      scst_e[(size_t)(spos+1)*H + 32*j + hp] = c2;   // trash-slot safe if no push
      float* h2dst = h2g + (size_t)(step&1)*NB*H;
      astore(h2dst + (size_t)ge*H + 32*j + hp, h2);
    } else if (tid < 256){
      const int t2 = tid - 128, r = t2 & 31, e = t2 >> 5;
      const int ge = ge0 + e;
      const int spos = ictl[e][0], bp = ictl[e][1];
      const double* ps = (const double*)(pb_zx + (size_t)ge*SEQ*G4 + (size_t)S2*G4);
      double s = SUp[0][e][r] + SUp[1][e][r] + SUp[2][e][r] + SUp[3][e][r]
               + SUp[4][e][r] + SUp[5][e][r] + SUp[6][e][r] + SUp[7][e][r]
               + ps[(size_t)spos*H + 32*j + r]
               + (double)ysumb_g[((size_t)ge*65 + bp)*H + 32*j + r]
               + (double)sum_b[32*j + r];
      astore(summg + (size_t)ge*H + 32*j + r, fmaxf((float)s, 0.f));
    }
    gbarl(ctr, 16u*step + 8u);

    // ---- phase B: gather summ, replicated logits/softmax/argmax/control
    {
      const int e = tid >> 8, h = tid & 255;
      smT[h][e] = aload(summg + (size_t)(ge0+e)*H + h);
    }
    __syncthreads();
    {
      const int o = tid & 63, cg = (tid>>6)&3, e = tid >> 8;
      const float* W = Wt_act + (size_t)(cg*64)*NA + o;
      double acc = 0.0;
      #pragma unroll 8
      for (int c = 0; c < 64; ++c)
        acc += (double)W[(size_t)c*NA] * (double)smT[cg*64 + c][e];
      Ld[cg][e][o] = acc;
    }
    __syncthreads();
    if (tid < 256){
      const int e = tid >> 6, o = tid & 63;   // wave e, lane o
      double v2 = (double)act_b[o] + Ld[0][e][o] + Ld[1][e][o] + Ld[2][e][o] + Ld[3][e][o];
      float v = (float)v2;
      float mx = v;
      #pragma unroll
      for (int o2 = 32; o2 > 0; o2 >>= 1) mx = fmaxf(mx, __shfl_xor(mx, o2));
      float ex = expf(v - mx), sm = ex;
      #pragma unroll
      for (int o2 = 32; o2 > 0; o2 >>= 1) sm += __shfl_xor(sm, o2);
      if (j == 0)
        out[((size_t)step*NB + (ge0+e))*NA + o] = v - mx - logf(sm);
      float bv = v; int bi = o;    // argmax, first index wins on ties
      #pragma unroll
      for (int o2 = 32; o2 > 0; o2 >>= 1){
        float ov = __shfl_xor(bv, o2); int oi = __shfl_xor(bi, o2);
        if (ov > bv || (ov == bv && oi < bi)){ bv = ov; bi = oi; }
      }
      if (o == 0) acts[e] = bi;
    }
    __syncthreads();

    // ---- hist gates (need action) + replicated control update
    if (tid < 128){
      const int hp = tid & 31, e = tid >> 5;
      const int a = acts[e];
      float z0=0.f,z1=0.f,z2=0.f,z3=0.f;
      #pragma unroll
      for (int cg = 0; cg < 8; ++cg){
        z0 += Zp[cg][0][0*32+hp];   // dummy to keep symmetry? no -- see below
      }
      // correct per-elem accumulation (rows: gate q at q*32+hp of slice)
      z0 = 0.f; z1 = 0.f; z2 = 0.f; z3 = 0.f;
      #pragma unroll
      for (int cg = 0; cg < 8; ++cg){
        z0 += Zp[cg][e][0*32+hp];
        z1 += Zp[cg][e][1*32+hp];
        z2 += Zp[cg][e][2*32+hp];
        z3 += Zp[cg][e][3*32+hp];
      }
      const float* hb = histxz + (size_t)a*G4;
      z0 += hb[0*H + 32*j + hp];
      z1 += hb[1*H + 32*j + hp];
      z2 += hb[2*H + 32*j + hp];
      z3 += hb[3*H + 32*j + hp];
      float hc = achL[e][hp];
      float c2 = sigf(z1)*hc + sigf(z0)*tanhf(z2);
      float h2v = sigf(z3)*tanhf(c2);
      achL[e][hp] = c2;
      astore(ahg + (size_t)(ge0+e)*H + 32*j + hp, h2v);
    } else if (tid < 132){
      const int e = tid - 128;
      const int a = acts[e];
      int sp = ictl[e][0], bp = ictl[e][1];
      int sop = stack_map[a], bop = buffer_map[a];
      if (sp == 0 && sop == -1) sop = 0;
      if (sp >= S1 - 1 && sop == 1) sop = 0;
      if (bp == 0 && bop == -1) bop = 0;
      int sposn = sp + sop;
      int bposn = bp + bop;
      int ne    = (bposn > 0) ? 1 : 0;
      int gidx  = bposn - 1; if (gidx < 0) gidx = 0; if (gidx > SEQ - 1) gidx = SEQ - 1;
      ictl[e][3] = sp + 1;          // commit slot for this step's candidate h2
      ictl[e][0] = sposn; ictl[e][1] = bposn; ictl[e][2] = ne ? gidx : SEQ;
    }
    gbarl(ctr, 16u*step + 16u);
  }
}

extern "C" void kernel_launch(void* const* d_in, const int* in_sizes, int n_in,
                              void* d_out, int out_size, void* d_ws, size_t ws_size,
                              hipStream_t stream){
  (void)in_sizes; (void)n_in; (void)out_size; (void)ws_size;
  const int*   tokens    = (const int*)  d_in[0];
  const float* word_emb  = (const float*)d_in[1];
  const float* compose_W = (const float*)d_in[2];
  const float* compose_b = (const float*)d_in[3];
  const float* h0        = (const float*)d_in[4];
  const float* c0        = (const float*)d_in[5];
  const float* pb_Wih    = (const float*)d_in[6];
  const float* pb_Whh    = (const float*)d_in[7];
  const float* pb_bih    = (const float*)d_in[8];
  const float* pb_bhh    = (const float*)d_in[9];
  const float* st_Wih    = (const float*)d_in[10];
  const float* st_Whh    = (const float*)d_in[11];
  const float* st_bih    = (const float*)d_in[12];
  const float* st_bhh    = (const float*)d_in[13];
  const float* hist_Wih  = (const float*)d_in[14];
  const float* hist_Whh  = (const float*)d_in[15];
  const float* hist_bih  = (const float*)d_in[16];
  const float* hist_bhh  = (const float*)d_in[17];
  const float* sum_W     = (const float*)d_in[18];
  const float* sum_b     = (const float*)d_in[19];
  const float* act_W     = (const float*)d_in[20];
  const float* act_b     = (const float*)d_in[21];
  const float* action_emb= (const float*)d_in[22];
  const int*   stack_map = (const int*)  d_in[23];
  const int*   buffer_map= (const int*)  d_in[24];

  float* ws     = (float*)d_ws;
  float* pb_zx  = ws;                                  // 128*64*1024 (arena: pzs[42]+psums[42] per elem)
  float* st_zx  = pb_zx + (size_t)NB*SEQ*G4;           // 128*65*1024
  float* bufh   = st_zx + (size_t)NB*(SEQ+1)*G4;       // 128*64*256
  float* scst   = bufh  + (size_t)NB*SEQ*H;            // 128*42*256
  float* histxz = scst  + (size_t)NB*S2*H;             // 64*1024
  float* Wt_pb  = histxz + (size_t)NA*G4;              // [256][1024]
  float* Wst_r  = Wt_pb  + (size_t)H*G4;               // [256][1024] permuted
  float* Whi_r  = Wst_r  + (size_t)H*G4;               // [256][1024] permuted
  float* Wt_sum = Whi_r  + (size_t)H*G4;               // [768][256]
  float* Wt_act = Wt_sum + (size_t)768*H;              // [256][64]
  float* Wt_pbih= Wt_act + (size_t)H*NA;               // [128][1024]
  float* Wt_stih= Wt_pbih+ (size_t)DIN*G4;             // [128][1024]
  float* Wt_cmp = Wt_stih+ (size_t)DIN*G4;             // [256][128]
  float* ysumb  = Wt_cmp + (size_t)DE*DIN;             // [128][65][256]
  float* pz0    = ysumb  + (size_t)NB*65*H;            // [1024]
  double* psum0 = (double*)(pz0 + G4);                 // [256] f64
  float* ysumb0 = (float*)(psum0 + H);                 // [256]
  float* ahg    = ysumb0 + H;                          // [128][256]
  float* h2g    = ahg    + (size_t)NB*H;               // [2][128][256]
  float* summg  = h2g    + (size_t)2*NB*H;             // [128][256]
  unsigned* bars= (unsigned*)(summg + (size_t)NB*H);   // [32]

  hipMemsetAsync(bars, 0, 32*sizeof(unsigned), stream);

  dim3 blk(32, 8);
  transpose_k<<<dim3(256/32, 1024/32), blk, 0, stream>>>(pb_Whh,   Wt_pb,  1024, 256);
  perm_transpose_k<<<dim3(256/32, 32), blk, 0, stream>>>(st_Whh,   Wst_r);
  perm_transpose_k<<<dim3(256/32, 32), blk, 0, stream>>>(hist_Whh, Whi_r);
  transpose_k<<<dim3(768/32,  256/32), blk, 0, stream>>>(sum_W,    Wt_sum,  256, 768);
  transpose_k<<<dim3(256/32,   64/32), blk, 0, stream>>>(act_W,    Wt_act,   64, 256);
  transpose_k<<<dim3(128/32, 1024/32), blk, 0, stream>>>(pb_Wih,   Wt_pbih,1024, 128);
  transpose_k<<<dim3(128/32, 1024/32), blk, 0, stream>>>(st_Wih,   Wt_stih,1024, 128);
  transpose_k<<<dim3(256/32,  128/32), blk, 0, stream>>>(compose_W,Wt_cmp,  128, 256);
  hist_proj_kernel<<<dim3(NA), dim3(256), 0, stream>>>(hist_Wih, hist_bih, hist_bhh,
                                                       action_emb, histxz);
  h0_proj_kernel<<<dim3(1), dim3(256), 0, stream>>>(Wst_r, Wt_sum, h0, pz0, psum0, ysumb0);

  prologue_kernel<<<dim3(NB), dim3(1024), 0, stream>>>(tokens, word_emb, Wt_cmp, compose_b,
      h0, c0, Wt_pbih, Wt_pb, pb_bih, pb_bhh, Wt_stih, st_bih, st_bhh, Wt_sum,
      pb_zx, st_zx, bufh, scst, ysumb, pz0, psum0, ysumb0);

  step_kernel<<<dim3(256), dim3(1024), 0, stream>>>(Wst_r, Whi_r, Wt_sum, Wt_act,
      act_b, sum_b, stack_map, buffer_map, histxz, h0, c0,
      pb_zx, st_zx, scst, ysumb, ahg, h2g, summg, bars, (float*)d_out);
}

// Round 6
// 3420.095 us; speedup vs baseline: 2.1889x; 1.6932x over previous
//
#include <hip/hip_runtime.h>
#include <cmath>

constexpr int SEQ = 64;    // sequence length
constexpr int NB  = 128;   // batch
constexpr int H   = 256;   // hidden
constexpr int DIN = 128;   // composed token dim
constexpr int DE  = 256;   // word emb dim
constexpr int NA  = 64;    // actions
constexpr int S1  = 41;    // STACK_SIZE+1
constexpr int S2  = 42;    // slots incl trash slot 41 (unconditional writes)
constexpr int MS  = 100;   // max steps
constexpr int G4  = 1024;  // 4*H

__device__ __forceinline__ float sigf(float x){ return 1.0f/(1.0f+expf(-x)); }

// L2-bypassing (fabric-coherent) relaxed atomics for cross-block data.
__device__ __forceinline__ float aload(const float* p){
  return __hip_atomic_load((const float*)p, __ATOMIC_RELAXED, __HIP_MEMORY_SCOPE_AGENT);
}
__device__ __forceinline__ void astore(float* p, float v){
  __hip_atomic_store(p, v, __ATOMIC_RELAXED, __HIP_MEMORY_SCOPE_AGENT);
}

// Cheap group barrier: NO acquire/release cache maintenance. __syncthreads
// drains vmcnt (stores device-visible: all cross-block data uses bypass
// atomics), then relaxed fetch_add + relaxed poll. All 256 blocks co-resident
// (1 block/CU enforced by >80KB LDS). Counter per group on its own 128B line.
__device__ __forceinline__ void gbarl(unsigned* c, unsigned tgt){
  __syncthreads();
  if (threadIdx.x == 0){
    asm volatile("" ::: "memory");
    __hip_atomic_fetch_add(c, 1u, __ATOMIC_RELAXED, __HIP_MEMORY_SCOPE_AGENT);
    while (__hip_atomic_load(c, __ATOMIC_RELAXED, __HIP_MEMORY_SCOPE_AGENT) < tgt)
      __builtin_amdgcn_s_sleep(1);
    asm volatile("" ::: "memory");
  }
  __syncthreads();
}

// ---------------- transpose: in [R][C] -> out [C][R]
__global__ void transpose_k(const float* __restrict__ in, float* __restrict__ out,
                            int R, int C){
  __shared__ float t[32][33];
  int bx = blockIdx.x*32, by = blockIdx.y*32;
  int x = threadIdx.x, y = threadIdx.y;   // block 32x8
  #pragma unroll
  for (int j = 0; j < 32; j += 8)
    t[y+j][x] = in[(size_t)(by+y+j)*C + bx + x];
  __syncthreads();
  #pragma unroll
  for (int j = 0; j < 32; j += 8)
    out[(size_t)(bx+y+j)*R + by + x] = t[x][y+j];
}

// permuted transpose for [1024][256] weights -> [256][1024] with slice-major rows:
// out[c][ jj*128 + q*32 + r ] = in[ q*256 + jj*32 + r ][ c ]
__global__ void perm_transpose_k(const float* __restrict__ in, float* __restrict__ out){
  __shared__ float t[32][33];
  int bx = blockIdx.x*32;            // c-tile base
  int m  = blockIdx.y;               // source row-chunk (32 rows)
  int q = m >> 3, jj = m & 7;
  int by = q*256 + jj*32;            // source row base
  int nb = jj*128 + q*32;            // dest (permuted) row base
  int x = threadIdx.x, y = threadIdx.y;
  #pragma unroll
  for (int j = 0; j < 32; j += 8)
    t[y+j][x] = in[(size_t)(by+y+j)*256 + bx + x];
  __syncthreads();
  #pragma unroll
  for (int j = 0; j < 32; j += 8)
    out[(size_t)(bx+y+j)*1024 + nb + x] = t[x][y+j];
}

// hist_xz[a][r] = hist_Wih[r,:] . action_emb[a,:] + hist_bih[r] + hist_bhh[r]
__global__ void hist_proj_kernel(const float* __restrict__ Wih,
                                 const float* __restrict__ bih,
                                 const float* __restrict__ bhh,
                                 const float* __restrict__ aemb,
                                 float* __restrict__ out){
  int a = blockIdx.x, t = threadIdx.x;
  __shared__ float e[64];
  if (t < 64) e[t] = aemb[a*64 + t];
  __syncthreads();
  for (int r = t; r < G4; r += blockDim.x){
    const float* w = Wih + r*64;
    float acc = bih[r] + bhh[r];
    #pragma unroll
    for (int k = 0; k < 64; k += 4)
      acc += w[k]*e[k] + w[k+1]*e[k+1] + w[k+2]*e[k+2] + w[k+3]*e[k+3];
    out[a*G4 + r] = acc;
  }
}

// one-time projections of h0. Wt_st_r is the PERMUTED layout, so pz0 comes out
// in permuted row ordering (matching the step kernel's slice reads).
__global__ void h0_proj_kernel(const float* __restrict__ Wt_st_r,  // [256][1024] perm
                               const float* __restrict__ Wt_sum,   // [768][256]
                               const float* __restrict__ h0,
                               float* __restrict__ pz0,            // [1024] perm order
                               double* __restrict__ psum0,         // [256]
                               float* __restrict__ ysumb0){        // [256]
  __shared__ float h0l[H];
  const int t = threadIdx.x;   // 256 threads
  h0l[t] = h0[t];
  __syncthreads();
  float4 acc = make_float4(0.f,0.f,0.f,0.f);
  for (int c = 0; c < H; ++c){
    float4 w = ((const float4*)(Wt_st_r + (size_t)c*G4))[t];
    float x = h0l[c];
    acc.x += w.x*x; acc.y += w.y*x; acc.z += w.z*x; acc.w += w.w*x;
  }
  ((float4*)pz0)[t] = acc;
  double a0 = 0.0, a1 = 0.0;
  for (int c = 0; c < H; ++c){
    double x = (double)h0l[c];
    a0 += (double)Wt_sum[(size_t)c*H + t] * x;          // s-part
    a1 += (double)Wt_sum[(size_t)(H + c)*H + t] * x;    // b-part
  }
  psum0[t] = a0;
  ysumb0[t] = (float)a1;
}

// ---------------- prologue: per-element P0a/P0b/P1 + ysumb + slot-0 init.
// (verbatim round-3/4/5, correctness-validated)
__global__ __launch_bounds__(1024, 1)
void prologue_kernel(const int* __restrict__ tokens,
                     const float* __restrict__ word_emb,
                     const float* __restrict__ Wt_cmp,   // [256][128]
                     const float* __restrict__ compose_b,
                     const float* __restrict__ h0,
                     const float* __restrict__ c0,
                     const float* __restrict__ Wt_pbih,  // [128][1024]
                     const float* __restrict__ Wt_pb,    // [256][1024]
                     const float* __restrict__ pb_bih,
                     const float* __restrict__ pb_bhh,
                     const float* __restrict__ Wt_stih,  // [128][1024]
                     const float* __restrict__ st_bih,
                     const float* __restrict__ st_bhh,
                     const float* __restrict__ Wt_sum,   // [768][256]
                     float* __restrict__ pb_zx,   // [B][64][1024]; arena reused for pzs/psums
                     float* __restrict__ st_zx,   // [B][65][1024] (row 64 = bias only)
                     float* __restrict__ bufh,    // [B][64][256]
                     float* __restrict__ scst,    // [B][42][256]
                     float* __restrict__ ysumb_g, // [B][65][256]
                     const float* __restrict__ pz0,
                     const double* __restrict__ psum0,
                     const float* __restrict__ ysumb0)
{
  __shared__ __align__(16) float A[8192];
  __shared__ __align__(16) float Bx[4096];
  __shared__ __align__(16) float ahl[H];
  __shared__ __align__(16) float acl[H];
  __shared__ __align__(16) float h0l[H];

  const int b   = blockIdx.x;
  const int tid = threadIdx.x;

  float* tokl = A;               // [64][128] during P0
  float* embs = Bx;              // [16][256] during P0a

  float*  pzs_b   = pb_zx + (size_t)b*SEQ*G4;
  double* psums_b = (double*)(pzs_b + (size_t)S2*G4);
  float*  pbzx_b  = pb_zx + (size_t)b*SEQ*G4;
  float*  stzx_b  = st_zx + (size_t)b*(SEQ+1)*G4;
  float*  bufh_b  = bufh  + (size_t)b*SEQ*H;
  float*  scst_b  = scst  + (size_t)b*S2*H;
  float*  ysumb_b = ysumb_g + (size_t)b*65*H;

  if (tid < H) h0l[tid] = h0[tid];
  __syncthreads();

  // ---------------- P0a
  {
    const int d = tid & 127, tb = tid >> 7;
    const float cb = compose_b[d];
    for (int pass = 0; pass < 4; ++pass){
      for (int j = tid >> 8; j < 16; j += 4){
        int tt = pass*16 + j;
        int id = tokens[tt*NB + b];
        embs[j*DE + (tid & 255)] = word_emb[(size_t)id*DE + (tid & 255)];
      }
      __syncthreads();
      float a0 = 0.f, a1 = 0.f;
      const float* eb = embs + (tb*2)*DE;
      for (int c = 0; c < DE; ++c){
        float w = Wt_cmp[c*DIN + d];
        a0 += w*eb[c]; a1 += w*eb[DE + c];
      }
      int t0 = pass*16 + tb*2;
      tokl[(t0    )*DIN + d] = fmaxf(a0 + cb, 0.f);
      tokl[(t0 + 1)*DIN + d] = fmaxf(a1 + cb, 0.f);
      __syncthreads();
    }
  }

  // ---------------- P0b
  {
    const int m  = tid >> 9;
    const int lt = tid & 255;
    const int sub = (tid >> 8) & 1;
    const float* Wt  = m ? Wt_stih : Wt_pbih;
    float*       zxb = m ? stzx_b : pbzx_b;
    const float* bA  = m ? st_bih : pb_bih;
    const float* bB  = m ? st_bhh : pb_bhh;
    float4 x1 = ((const float4*)bA)[lt], x2 = ((const float4*)bB)[lt];
    float bx = x1.x + x2.x, by = x1.y + x2.y, bz = x1.z + x2.z, bw = x1.w + x2.w;
    for (int blk = 0; blk < 4; ++blk){
      float ax[8], ay[8], az[8], aw[8];
      #pragma unroll
      for (int t = 0; t < 8; ++t){ ax[t]=0.f; ay[t]=0.f; az[t]=0.f; aw[t]=0.f; }
      const float* tb = tokl + (blk*16 + sub*8)*DIN;
      for (int c = 0; c < DIN; ++c){
        float4 w = ((const float4*)(Wt + (size_t)c*G4))[lt];
        #pragma unroll
        for (int t = 0; t < 8; ++t){
          float x = tb[t*DIN + c];
          ax[t] += w.x*x; ay[t] += w.y*x; az[t] += w.z*x; aw[t] += w.w*x;
        }
      }
      #pragma unroll
      for (int t = 0; t < 8; ++t){
        float4 r = make_float4(ax[t]+bx, ay[t]+by, az[t]+bz, aw[t]+bw);
        ((float4*)(zxb + (size_t)(blk*16 + sub*8 + t)*G4))[lt] = r;
      }
    }
    if (m == 1 && sub == 0)
      ((float4*)(zxb + (size_t)SEQ*G4))[lt] = make_float4(bx, by, bz, bw);
  }
  __syncthreads();

  // ---------------- P1: pre-buffer LSTM over reversed tokens
  if (tid < H){ ahl[tid] = h0l[tid]; acl[tid] = c0[tid]; }
  __syncthreads();
  for (int k = 0; k < SEQ; ++k){
    const int tt = SEQ - 1 - k;
    {
      const int q = tid & 255, cg = tid >> 8;
      float a0=0.f, a1=0.f, a2=0.f, a3=0.f;
      const int cb2 = cg*64;
      for (int c = cb2; c < cb2 + 64; ++c){
        float4 w = ((const float4*)(Wt_pb + (size_t)c*G4))[q];
        float x = ahl[c];
        a0 += w.x*x; a1 += w.y*x; a2 += w.z*x; a3 += w.w*x;
      }
      ((float4*)(A + cg*G4))[q] = make_float4(a0, a1, a2, a3);
    }
    __syncthreads();
    if (tid < H){
      const float* zx = pbzx_b + (size_t)tt*G4;
      float zi_ = A[tid]     + A[G4+tid]     + A[2*G4+tid]     + A[3*G4+tid]     + zx[tid];
      float zf_ = A[H+tid]   + A[G4+H+tid]   + A[2*G4+H+tid]   + A[3*G4+H+tid]   + zx[H+tid];
      float zg_ = A[2*H+tid] + A[G4+2*H+tid] + A[2*G4+2*H+tid] + A[3*G4+2*H+tid] + zx[2*H+tid];
      float zo_ = A[3*H+tid] + A[G4+3*H+tid] + A[2*G4+3*H+tid] + A[3*G4+3*H+tid] + zx[3*H+tid];
      float c2 = sigf(zf_)*acl[tid] + sigf(zi_)*tanhf(zg_);
      float h2 = sigf(zo_)*tanhf(c2);
      acl[tid] = c2; ahl[tid] = h2;
      bufh_b[(size_t)k*H + tid] = h2;
    }
    __syncthreads();
  }
  // pb_zx rows dead now; arena (pzs/psums) writable.

  // ---------------- slot-0 init + scst init
  if (tid < 256) ((float4*)pzs_b)[tid] = ((const float4*)pz0)[tid];   // perm order
  if (tid < 256) psums_b[tid] = psum0[tid];
  if (tid < 64)  ((float4*)ysumb_b)[tid] = ((const float4*)ysumb0)[tid];
  for (int i = tid; i < S2*H; i += 1024) scst_b[i] = (i < H) ? c0[i] : 0.f;

  // ---------------- ysumb[j] = Wsum_b @ bufh[j-1], j=1..64 (f64 acc)
  {
    const int lt = tid & 63, wv = tid >> 6;
    double a00=0,a01=0,a02=0,a03=0, a10=0,a11=0,a12=0,a13=0;
    double a20=0,a21=0,a22=0,a23=0, a30=0,a31=0,a32=0,a33=0;
    for (int c = 0; c < H; ++c){
      float4 w = ((const float4*)(Wt_sum + (size_t)(H + c)*H))[lt];
      double x0 = (double)bufh_b[(size_t)(wv     )*H + c];
      double x1 = (double)bufh_b[(size_t)(wv + 16)*H + c];
      double x2 = (double)bufh_b[(size_t)(wv + 32)*H + c];
      double x3 = (double)bufh_b[(size_t)(wv + 48)*H + c];
      a00+=(double)w.x*x0; a01+=(double)w.y*x0; a02+=(double)w.z*x0; a03+=(double)w.w*x0;
      a10+=(double)w.x*x1; a11+=(double)w.y*x1; a12+=(double)w.z*x1; a13+=(double)w.w*x1;
      a20+=(double)w.x*x2; a21+=(double)w.y*x2; a22+=(double)w.z*x2; a23+=(double)w.w*x2;
      a30+=(double)w.x*x3; a31+=(double)w.y*x3; a32+=(double)w.z*x3; a33+=(double)w.w*x3;
    }
    ((float4*)(ysumb_b + (size_t)(wv+ 1)*H))[lt] = make_float4((float)a00,(float)a01,(float)a02,(float)a03);
    ((float4*)(ysumb_b + (size_t)(wv+17)*H))[lt] = make_float4((float)a10,(float)a11,(float)a12,(float)a13);
    ((float4*)(ysumb_b + (size_t)(wv+33)*H))[lt] = make_float4((float)a20,(float)a21,(float)a22,(float)a23);
    ((float4*)(ysumb_b + (size_t)(wv+49)*H))[lt] = make_float4((float)a30,(float)a31,(float)a32,(float)a33);
  }
}

// ---------------- step kernel: 256 blocks x 1024 thr. Group = 8 blocks
// (j = blockIdx&7 = row-slice id) serving 4 elements. Slot caches owner-local.
// 2 relaxed group barriers/step; cross-block data via fabric-coherent relaxed
// atomics. Logits/argmax/control REPLICATED (bit-identical) in all 8 blocks.
// Wt_act pinned in LDS (also pushes LDS >80KB -> exactly 1 block/CU).
__global__ __launch_bounds__(1024, 1)
void step_kernel(const float* __restrict__ Wst_r,   // [256][1024] perm rows
                 const float* __restrict__ Whi_r,   // [256][1024] perm rows
                 const float* __restrict__ Wt_sum,  // [768][256]
                 const float* __restrict__ Wt_act,  // [256][64]
                 const float* __restrict__ act_b,
                 const float* __restrict__ sum_b,
                 const int* __restrict__ stack_map,
                 const int* __restrict__ buffer_map,
                 const float* __restrict__ histxz,  // [64][1024] original order
                 const float* __restrict__ h0,
                 const float* __restrict__ c0,
                 float* __restrict__ pb_zx,         // arena: pzs[42][1024](perm) + psums[42][256] f64
                 const float* __restrict__ st_zx,   // [B][65][1024] original order
                 float* __restrict__ scst,          // [B][42][256]
                 const float* __restrict__ ysumb_g, // [B][65][256]
                 float* __restrict__ ahg,           // [B][256]
                 float* __restrict__ h2g,           // [2][B][256] (step-parity dbuf)
                 float* __restrict__ summg,         // [B][256]
                 unsigned* __restrict__ bars,       // [32 groups][32] (128B-padded)
                 float* __restrict__ out)           // [100][128][64]
{
  __shared__ __align__(16) float  WaL[H*NA];       // 64KB Wt_act cache
  __shared__ __align__(16) float  ahT[256][4];
  __shared__ __align__(16) float  h2T[256][4];
  __shared__ __align__(16) float  smT[256][4];
  __shared__ __align__(16) float  Zp[8][4][128];   // hist-z partials [cg][e][row]
  __shared__ __align__(16) float  Pp[8][4][128];   // st-z partials
  __shared__ __align__(16) double SUp[8][4][32];   // suma partials [cg][e][r]
  __shared__ __align__(16) double SPp[8][4][32];   // psums partials
  __shared__ __align__(16) double Ld[4][4][64];    // logits partials [cg][e][o]
  __shared__ __align__(16) float  achL[4][32];     // hist c slice (owner-local)
  __shared__ int ictl[4][4];   // per elem: spos, bpos, sinc, sp1 (commit slot)
  __shared__ int acts[4];

  const int tid = threadIdx.x;
  const int j   = blockIdx.x & 7;        // row-slice id
  const int g   = blockIdx.x >> 3;       // group
  const int ge0 = g*4;
  unsigned* ctr = bars + g*32;           // own 128B line per group

  // preload Wt_act into LDS (coalesced float4)
  {
    const float4* src = (const float4*)Wt_act;
    float4* dst = (float4*)WaL;
    #pragma unroll
    for (int i = 0; i < 4; ++i) dst[i*1024 + tid] = src[i*1024 + tid];
  }
  if (tid < 128) achL[tid>>5][tid&31] = c0[32*j + (tid&31)];
  if (tid < 4){ ictl[tid][0] = 0; ictl[tid][1] = SEQ; ictl[tid][2] = SEQ - 1; ictl[tid][3] = 1; }
  __syncthreads();

  for (int step = 0; step < MS; ++step){
    // ---- gather ah / prev candidate h2 (fabric reads; parity dbuf for h2)
    {
      const int e = tid >> 8, h = tid & 255;
      ahT[h][e] = (step == 0) ? h0[h] : aload(ahg + (size_t)(ge0+e)*H + h);
      if (step){
        const float* h2src = h2g + (size_t)((step+1)&1)*NB*H;
        h2T[h][e] = aload(h2src + (size_t)(ge0+e)*H + h);
      }
    }
    __syncthreads();

    // ---- A1: hist-z partials over this block's row slice
    {
      const int rl = tid & 127, cg = tid >> 7;
      const float* W = Whi_r + (size_t)(cg*32)*G4 + j*128 + rl;
      float a0=0.f,a1=0.f,a2=0.f,a3=0.f;
      #pragma unroll 8
      for (int c = 0; c < 32; ++c){
        float w = W[(size_t)c*G4];
        float4 x = *(const float4*)&ahT[cg*32 + c][0];
        a0 += w*x.x; a1 += w*x.y; a2 += w*x.z; a3 += w*x.w;
      }
      Zp[cg][0][rl]=a0; Zp[cg][1][rl]=a1; Zp[cg][2][rl]=a2; Zp[cg][3][rl]=a3;
    }
    if (step){
      const int rl = tid & 127, cg = tid >> 7;
      const float* W = Wst_r + (size_t)(cg*32)*G4 + j*128 + rl;
      float a0=0.f,a1=0.f,a2=0.f,a3=0.f;
      #pragma unroll 8
      for (int c = 0; c < 32; ++c){
        float w = W[(size_t)c*G4];
        float4 x = *(const float4*)&h2T[cg*32 + c][0];
        a0 += w*x.x; a1 += w*x.y; a2 += w*x.z; a3 += w*x.w;
      }
      Pp[cg][0][rl]=a0; Pp[cg][1][rl]=a1; Pp[cg][2][rl]=a2; Pp[cg][3][rl]=a3;
    }
    // ---- A2: suma f64 partials
    {
      const int r = tid & 31, e = (tid>>5)&3, cg = tid >> 7;
      const float* W = Wt_sum + (size_t)(512 + cg*32)*H + 32*j + r;
      double a = 0.0;
      #pragma unroll 8
      for (int c = 0; c < 32; ++c)
        a += (double)W[(size_t)c*H] * (double)ahT[cg*32 + c][e];
      SUp[cg][e][r] = a;
    }
    if (step){
      const int r = tid & 31, e = (tid>>5)&3, cg = tid >> 7;
      const float* W = Wt_sum + (size_t)(cg*32)*H + 32*j + r;
      double a = 0.0;
      #pragma unroll 8
      for (int c = 0; c < 32; ++c)
        a += (double)W[(size_t)c*H] * (double)h2T[cg*32 + c][e];
      SPp[cg][e][r] = a;
    }
    __syncthreads();

    // ---- alpha: commit prev h2's projections into slot caches (owner-local)
    if (step){
      if (tid < 512){
        const int rl = tid & 127, e = tid >> 7;
        float v = Pp[0][e][rl] + Pp[1][e][rl] + Pp[2][e][rl] + Pp[3][e][rl]
                + Pp[4][e][rl] + Pp[5][e][rl] + Pp[6][e][rl] + Pp[7][e][rl];
        float* pzs_e = pb_zx + (size_t)(ge0+e)*SEQ*G4;
        pzs_e[(size_t)ictl[e][3]*G4 + j*128 + rl] = v;
      } else if (tid < 640){
        const int t2 = tid - 512, r = t2 & 31, e = t2 >> 5;
        double v = SPp[0][e][r] + SPp[1][e][r] + SPp[2][e][r] + SPp[3][e][r]
                 + SPp[4][e][r] + SPp[5][e][r] + SPp[6][e][r] + SPp[7][e][r];
        double* ps = (double*)(pb_zx + (size_t)(ge0+e)*SEQ*G4 + (size_t)S2*G4);
        ps[(size_t)ictl[e][3]*H + 32*j + r] = v;
      }
      __syncthreads();
    }

    // ---- beta: st-LSTM gates + summ finalize (owner-local slot reads)
    if (tid < 128){
      const int hp = tid & 31, e = tid >> 5;
      const int ge = ge0 + e;
      const int spos = ictl[e][0], sinc = ictl[e][2];
      const float* pz = pb_zx + (size_t)ge*SEQ*G4 + (size_t)spos*G4 + j*128;
      const float* zx = st_zx + (size_t)ge*(SEQ+1)*G4 + (size_t)sinc*G4;
      float zi = pz[0*32+hp] + zx[0*H + 32*j + hp];
      float zf = pz[1*32+hp] + zx[1*H + 32*j + hp];
      float zg = pz[2*32+hp] + zx[2*H + 32*j + hp];
      float zo = pz[3*32+hp] + zx[3*H + 32*j + hp];
      float* scst_e = scst + (size_t)ge*S2*H;
      float ct = scst_e[(size_t)spos*H + 32*j + hp];
      float c2 = sigf(zf)*ct + sigf(zi)*tanhf(zg);
      float h2 = sigf(zo)*tanhf(c2);
      scst_e[(size_t)(spos+1)*H + 32*j + hp] = c2;   // trash-slot safe if no push
      float* h2dst = h2g + (size_t)(step&1)*NB*H;
      astore(h2dst + (size_t)ge*H + 32*j + hp, h2);
    } else if (tid < 256){
      const int t2 = tid - 128, r = t2 & 31, e = t2 >> 5;
      const int ge = ge0 + e;
      const int spos = ictl[e][0], bp = ictl[e][1];
      const double* ps = (const double*)(pb_zx + (size_t)ge*SEQ*G4 + (size_t)S2*G4);
      double s = SUp[0][e][r] + SUp[1][e][r] + SUp[2][e][r] + SUp[3][e][r]
               + SUp[4][e][r] + SUp[5][e][r] + SUp[6][e][r] + SUp[7][e][r]
               + ps[(size_t)spos*H + 32*j + r]
               + (double)ysumb_g[((size_t)ge*65 + bp)*H + 32*j + r]
               + (double)sum_b[32*j + r];
      astore(summg + (size_t)ge*H + 32*j + r, fmaxf((float)s, 0.f));
    }
    gbarl(ctr, 16u*step + 8u);

    // ---- phase B: gather summ, replicated logits/softmax/argmax/control
    {
      const int e = tid >> 8, h = tid & 255;
      smT[h][e] = aload(summg + (size_t)(ge0+e)*H + h);
    }
    __syncthreads();
    {
      const int o = tid & 63, cg = (tid>>6)&3, e = tid >> 8;
      const float* W = WaL + (size_t)(cg*64)*NA + o;
      double acc = 0.0;
      #pragma unroll 8
      for (int c = 0; c < 64; ++c)
        acc += (double)W[(size_t)c*NA] * (double)smT[cg*64 + c][e];
      Ld[cg][e][o] = acc;
    }
    __syncthreads();
    if (tid < 256){
      const int e = tid >> 6, o = tid & 63;   // wave e, lane o
      double v2 = (double)act_b[o] + Ld[0][e][o] + Ld[1][e][o] + Ld[2][e][o] + Ld[3][e][o];
      float v = (float)v2;
      float mx = v;
      #pragma unroll
      for (int o2 = 32; o2 > 0; o2 >>= 1) mx = fmaxf(mx, __shfl_xor(mx, o2));
      float ex = expf(v - mx), sm = ex;
      #pragma unroll
      for (int o2 = 32; o2 > 0; o2 >>= 1) sm += __shfl_xor(sm, o2);
      if (j == 0)
        out[((size_t)step*NB + (ge0+e))*NA + o] = v - mx - logf(sm);
      float bv = v; int bi = o;    // argmax, first index wins on ties
      #pragma unroll
      for (int o2 = 32; o2 > 0; o2 >>= 1){
        float ov = __shfl_xor(bv, o2); int oi = __shfl_xor(bi, o2);
        if (ov > bv || (ov == bv && oi < bi)){ bv = ov; bi = oi; }
      }
      if (o == 0) acts[e] = bi;
    }
    __syncthreads();

    // ---- hist gates (need action) + replicated control update
    if (tid < 128){
      const int hp = tid & 31, e = tid >> 5;
      const int a = acts[e];
      float z0 = 0.f, z1 = 0.f, z2 = 0.f, z3 = 0.f;
      #pragma unroll
      for (int cg = 0; cg < 8; ++cg){
        z0 += Zp[cg][e][0*32+hp];
        z1 += Zp[cg][e][1*32+hp];
        z2 += Zp[cg][e][2*32+hp];
        z3 += Zp[cg][e][3*32+hp];
      }
      const float* hb = histxz + (size_t)a*G4;
      z0 += hb[0*H + 32*j + hp];
      z1 += hb[1*H + 32*j + hp];
      z2 += hb[2*H + 32*j + hp];
      z3 += hb[3*H + 32*j + hp];
      float hc = achL[e][hp];
      float c2 = sigf(z1)*hc + sigf(z0)*tanhf(z2);
      float h2v = sigf(z3)*tanhf(c2);
      achL[e][hp] = c2;
      astore(ahg + (size_t)(ge0+e)*H + 32*j + hp, h2v);
    } else if (tid < 132){
      const int e = tid - 128;
      const int a = acts[e];
      int sp = ictl[e][0], bp = ictl[e][1];
      int sop = stack_map[a], bop = buffer_map[a];
      if (sp == 0 && sop == -1) sop = 0;
      if (sp >= S1 - 1 && sop == 1) sop = 0;
      if (bp == 0 && bop == -1) bop = 0;
      int sposn = sp + sop;
      int bposn = bp + bop;
      int ne    = (bposn > 0) ? 1 : 0;
      int gidx  = bposn - 1; if (gidx < 0) gidx = 0; if (gidx > SEQ - 1) gidx = SEQ - 1;
      ictl[e][3] = sp + 1;          // commit slot for this step's candidate h2
      ictl[e][0] = sposn; ictl[e][1] = bposn; ictl[e][2] = ne ? gidx : SEQ;
    }
    gbarl(ctr, 16u*step + 16u);
  }
}

extern "C" void kernel_launch(void* const* d_in, const int* in_sizes, int n_in,
                              void* d_out, int out_size, void* d_ws, size_t ws_size,
                              hipStream_t stream){
  (void)in_sizes; (void)n_in; (void)out_size; (void)ws_size;
  const int*   tokens    = (const int*)  d_in[0];
  const float* word_emb  = (const float*)d_in[1];
  const float* compose_W = (const float*)d_in[2];
  const float* compose_b = (const float*)d_in[3];
  const float* h0        = (const float*)d_in[4];
  const float* c0        = (const float*)d_in[5];
  const float* pb_Wih    = (const float*)d_in[6];
  const float* pb_Whh    = (const float*)d_in[7];
  const float* pb_bih    = (const float*)d_in[8];
  const float* pb_bhh    = (const float*)d_in[9];
  const float* st_Wih    = (const float*)d_in[10];
  const float* st_Whh    = (const float*)d_in[11];
  const float* st_bih    = (const float*)d_in[12];
  const float* st_bhh    = (const float*)d_in[13];
  const float* hist_Wih  = (const float*)d_in[14];
  const float* hist_Whh  = (const float*)d_in[15];
  const float* hist_bih  = (const float*)d_in[16];
  const float* hist_bhh  = (const float*)d_in[17];
  const float* sum_W     = (const float*)d_in[18];
  const float* sum_b     = (const float*)d_in[19];
  const float* act_W     = (const float*)d_in[20];
  const float* act_b     = (const float*)d_in[21];
  const float* action_emb= (const float*)d_in[22];
  const int*   stack_map = (const int*)  d_in[23];
  const int*   buffer_map= (const int*)  d_in[24];

  float* ws     = (float*)d_ws;
  float* pb_zx  = ws;                                  // 128*64*1024 (arena: pzs[42]+psums[42] per elem)
  float* st_zx  = pb_zx + (size_t)NB*SEQ*G4;           // 128*65*1024
  float* bufh   = st_zx + (size_t)NB*(SEQ+1)*G4;       // 128*64*256
  float* scst   = bufh  + (size_t)NB*SEQ*H;            // 128*42*256
  float* histxz = scst  + (size_t)NB*S2*H;             // 64*1024
  float* Wt_pb  = histxz + (size_t)NA*G4;              // [256][1024]
  float* Wst_r  = Wt_pb  + (size_t)H*G4;               // [256][1024] permuted
  float* Whi_r  = Wst_r  + (size_t)H*G4;               // [256][1024] permuted
  float* Wt_sum = Whi_r  + (size_t)H*G4;               // [768][256]
  float* Wt_act = Wt_sum + (size_t)768*H;              // [256][64]
  float* Wt_pbih= Wt_act + (size_t)H*NA;               // [128][1024]
  float* Wt_stih= Wt_pbih+ (size_t)DIN*G4;             // [128][1024]
  float* Wt_cmp = Wt_stih+ (size_t)DIN*G4;             // [256][128]
  float* ysumb  = Wt_cmp + (size_t)DE*DIN;             // [128][65][256]
  float* pz0    = ysumb  + (size_t)NB*65*H;            // [1024]
  double* psum0 = (double*)(pz0 + G4);                 // [256] f64
  float* ysumb0 = (float*)(psum0 + H);                 // [256]
  float* ahg    = ysumb0 + H;                          // [128][256]
  float* h2g    = ahg    + (size_t)NB*H;               // [2][128][256]
  float* summg  = h2g    + (size_t)2*NB*H;             // [128][256]
  unsigned* bars= (unsigned*)(summg + (size_t)NB*H);   // [32][32] (128B-padded counters)

  hipMemsetAsync(bars, 0, 32*32*sizeof(unsigned), stream);

  dim3 blk(32, 8);
  transpose_k<<<dim3(256/32, 1024/32), blk, 0, stream>>>(pb_Whh,   Wt_pb,  1024, 256);
  perm_transpose_k<<<dim3(256/32, 32), blk, 0, stream>>>(st_Whh,   Wst_r);
  perm_transpose_k<<<dim3(256/32, 32), blk, 0, stream>>>(hist_Whh, Whi_r);
  transpose_k<<<dim3(768/32,  256/32), blk, 0, stream>>>(sum_W,    Wt_sum,  256, 768);
  transpose_k<<<dim3(256/32,   64/32), blk, 0, stream>>>(act_W,    Wt_act,   64, 256);
  transpose_k<<<dim3(128/32, 1024/32), blk, 0, stream>>>(pb_Wih,   Wt_pbih,1024, 128);
  transpose_k<<<dim3(128/32, 1024/32), blk, 0, stream>>>(st_Wih,   Wt_stih,1024, 128);
  transpose_k<<<dim3(256/32,  128/32), blk, 0, stream>>>(compose_W,Wt_cmp,  128, 256);
  hist_proj_kernel<<<dim3(NA), dim3(256), 0, stream>>>(hist_Wih, hist_bih, hist_bhh,
                                                       action_emb, histxz);
  h0_proj_kernel<<<dim3(1), dim3(256), 0, stream>>>(Wst_r, Wt_sum, h0, pz0, psum0, ysumb0);

  prologue_kernel<<<dim3(NB), dim3(1024), 0, stream>>>(tokens, word_emb, Wt_cmp, compose_b,
      h0, c0, Wt_pbih, Wt_pb, pb_bih, pb_bhh, Wt_stih, st_bih, st_bhh, Wt_sum,
      pb_zx, st_zx, bufh, scst, ysumb, pz0, psum0, ysumb0);

  step_kernel<<<dim3(256), dim3(1024), 0, stream>>>(Wst_r, Whi_r, Wt_sum, Wt_act,
      act_b, sum_b, stack_map, buffer_map, histxz, h0, c0,
      pb_zx, st_zx, scst, ysumb, ahg, h2g, summg, bars, (float*)d_out);
}